// Round 1
// baseline (933.524 us; speedup 1.0000x reference)
//
#include <hip/hip_runtime.h>

#define NN 100000
#define NE 1600000

// ---------------------------------------------------------------- degrees
__global__ void deg_kernel(const int* __restrict__ src, const int* __restrict__ dst,
                           int* __restrict__ outd, int* __restrict__ ind, int E) {
    int i = blockIdx.x * blockDim.x + threadIdx.x;
    if (i < E) {
        atomicAdd(&outd[src[i]], 1);
        atomicAdd(&ind[dst[i]], 1);
    }
}

__global__ void ds_kernel(const int* __restrict__ outd, const int* __restrict__ ind,
                          float* __restrict__ dso, float* __restrict__ dsi, int N) {
    int i = blockIdx.x * blockDim.x + threadIdx.x;
    if (i < N) {
        int od = outd[i], id = ind[i];
        dso[i] = od > 0 ? rsqrtf((float)od) : 1.0f;
        dsi[i] = id > 0 ? rsqrtf((float)id) : 1.0f;
    }
}

// ---------------------------------------------------------------- scan (row_start)
// scan1: blocks of 1024 elems (256 thr x 4). Writes inclusive scan into rs, block total into bsum.
__global__ __launch_bounds__(256) void scan1_kernel(const int* __restrict__ deg,
                                                    int* __restrict__ rs,
                                                    int* __restrict__ bsum, int N) {
    __shared__ int lds[256];
    int t = threadIdx.x, b = blockIdx.x;
    int base = b * 1024 + t * 4;
    int v0 = 0, v1 = 0, v2 = 0, v3 = 0;
    if (base + 0 < N) v0 = deg[base + 0];
    if (base + 1 < N) v1 = deg[base + 1];
    if (base + 2 < N) v2 = deg[base + 2];
    if (base + 3 < N) v3 = deg[base + 3];
    lds[t] = v0 + v1 + v2 + v3;
    __syncthreads();
    for (int off = 1; off < 256; off <<= 1) {
        int add = (t >= off) ? lds[t - off] : 0;
        __syncthreads();
        lds[t] += add;
        __syncthreads();
    }
    int excl = (t > 0) ? lds[t - 1] : 0;
    if (t == 255) bsum[b] = lds[255];
    int r0 = excl + v0, r1 = r0 + v1, r2 = r1 + v2, r3 = r2 + v3;
    if (base + 0 < N) rs[base + 0] = r0;
    if (base + 1 < N) rs[base + 1] = r1;
    if (base + 2 < N) rs[base + 2] = r2;
    if (base + 3 < N) rs[base + 3] = r3;
}

// scan2: single block of 128 threads scans <=128 block sums (exclusive, in place).
__global__ void scan2_kernel(int* __restrict__ bsum, int NB) {
    __shared__ int lds[128];
    int t = threadIdx.x;
    lds[t] = (t < NB) ? bsum[t] : 0;
    __syncthreads();
    for (int off = 1; off < 128; off <<= 1) {
        int add = (t >= off) ? lds[t - off] : 0;
        __syncthreads();
        lds[t] += add;
        __syncthreads();
    }
    if (t < NB) bsum[t] = (t > 0) ? lds[t - 1] : 0;
}

// scan3: rs[i] = inclusive - deg + block offset  -> exclusive row start
__global__ void scan3_kernel(int* __restrict__ rs, const int* __restrict__ deg,
                             const int* __restrict__ bsum, int N) {
    int i = blockIdx.x * blockDim.x + threadIdx.x;
    if (i < N) rs[i] = rs[i] - deg[i] + bsum[i >> 10];
}

// ---------------------------------------------------------------- CSR fill (counting sort by dst)
__global__ void fill_kernel(const int* __restrict__ src, const int* __restrict__ dst,
                            const int* __restrict__ rs, int* __restrict__ cur,
                            const float* __restrict__ dso,
                            int* __restrict__ eidx, float* __restrict__ ewgt, int E) {
    int i = blockIdx.x * blockDim.x + threadIdx.x;
    if (i < E) {
        int d = dst[i];
        int slot = atomicAdd(&cur[d], 1);
        int p = rs[d] + slot;
        int s = src[i];
        eidx[p] = s;
        ewgt[p] = dso[s];
    }
}

// ---------------------------------------------------------------- fused dual GEMM: U = X@W, V = X@L (+bias)
// X: [N][128] (optionally BN+ReLU applied on the fly), W/L: [128][MOUT]
// 256 threads, 32 rows/block. Each thread: 4 rows x 4 cols x 2 outputs.
template <int MOUT, bool BN>
__global__ __launch_bounds__(256) void gemm2_kernel(
    const float* __restrict__ X, const float* __restrict__ W, const float* __restrict__ L,
    const float* __restrict__ bias, const float* __restrict__ scale,
    const float* __restrict__ shift, float* __restrict__ U, float* __restrict__ V, int N) {
    __shared__ __align__(16) float Xs[16][36];    // [kk][row], padded stride 36 (16B-aligned)
    __shared__ __align__(16) float Ws[16][MOUT];
    __shared__ __align__(16) float Ls[16][MOUT];
    const int tid = threadIdx.x;
    const int tx = tid & 31, ty = tid >> 5;
    const long rb = (long)blockIdx.x * 32;
    float accU[4][4] = {}, accV[4][4] = {};

    for (int k0 = 0; k0 < 128; k0 += 16) {
        // stage X chunk [32 rows][16 k] transposed into Xs[kk][r]
        {
            int e = tid * 2;
            int r = e >> 4, kk = e & 15;
            float2 xv = *(const float2*)&X[(rb + r) * 128 + k0 + kk];
            if (BN) {
                xv.x = fmaxf(fmaf(xv.x, scale[k0 + kk], shift[k0 + kk]), 0.f);
                xv.y = fmaxf(fmaf(xv.y, scale[k0 + kk + 1], shift[k0 + kk + 1]), 0.f);
            }
            Xs[kk][r] = xv.x;
            Xs[kk + 1][r] = xv.y;
        }
        // stage W/L chunk rows k0..k0+15 (contiguous in row-major)
        {
            const float4* Wc = (const float4*)(W + k0 * MOUT);
            const float4* Lc = (const float4*)(L + k0 * MOUT);
            float4* Wsf = (float4*)&Ws[0][0];
            float4* Lsf = (float4*)&Ls[0][0];
            for (int e4 = tid; e4 < 16 * MOUT / 4; e4 += 256) {
                Wsf[e4] = Wc[e4];
                Lsf[e4] = Lc[e4];
            }
        }
        __syncthreads();
        if (MOUT == 128 || tx < MOUT / 4) {
#pragma unroll
            for (int kk = 0; kk < 16; ++kk) {
                float4 xs = *(const float4*)&Xs[kk][ty * 4];
                float4 ws = *(const float4*)&Ws[kk][tx * 4];
                float4 ls = *(const float4*)&Ls[kk][tx * 4];
                float xa[4] = {xs.x, xs.y, xs.z, xs.w};
                float wa[4] = {ws.x, ws.y, ws.z, ws.w};
                float la[4] = {ls.x, ls.y, ls.z, ls.w};
#pragma unroll
                for (int i = 0; i < 4; ++i)
#pragma unroll
                    for (int j = 0; j < 4; ++j) {
                        accU[i][j] = fmaf(xa[i], wa[j], accU[i][j]);
                        accV[i][j] = fmaf(xa[i], la[j], accV[i][j]);
                    }
            }
        }
        __syncthreads();
    }
    if (MOUT == 128 || tx < MOUT / 4) {
#pragma unroll
        for (int i = 0; i < 4; ++i) {
            long row = rb + ty * 4 + i;
            float4 u = make_float4(accU[i][0], accU[i][1], accU[i][2], accU[i][3]);
            float4 vv = make_float4(accV[i][0], accV[i][1], accV[i][2], accV[i][3]);
            if (bias) {
                vv.x += bias[tx * 4 + 0];
                vv.y += bias[tx * 4 + 1];
                vv.z += bias[tx * 4 + 2];
                vv.w += bias[tx * 4 + 3];
            }
            *(float4*)&U[row * MOUT + tx * 4] = u;
            *(float4*)&V[row * MOUT + tx * 4] = vv;
        }
    }
}

// ---------------------------------------------------------------- SpMM: Y[n] = ds_in[n]*sum_e w_e*Uin[src_e] + addB[n]
// one wave per node; lane covers 2 channels (float2). addB may alias Y (in-place).
template <int D>
__global__ __launch_bounds__(256) void spmm_kernel(
    const float* __restrict__ Uin, const float* __restrict__ addB, float* __restrict__ Y,
    const int* __restrict__ eidx, const float* __restrict__ ewgt,
    const int* __restrict__ rs, const int* __restrict__ deg,
    const float* __restrict__ dsi, int N) {
    int wv = blockIdx.x * 4 + (threadIdx.x >> 6);
    int lane = threadIdx.x & 63;
    if (wv >= N) return;
    int start = rs[wv];
    int dg = deg[wv];
    const bool act = (D == 128) || (lane < D / 2);
    const int c = lane * 2;
    float2 acc = make_float2(0.f, 0.f);
    for (int j0 = 0; j0 < dg; j0 += 64) {
        int m = min(64, dg - j0);
        int sidx = 0;
        float w = 0.f;
        if (lane < m) {
            sidx = eidx[start + j0 + lane];
            w = ewgt[start + j0 + lane];
        }
        for (int j = 0; j < m; ++j) {
            int s = __shfl(sidx, j);
            float ww = __shfl(w, j);
            if (act) {
                float2 xv = *(const float2*)&Uin[(long)s * D + c];
                acc.x = fmaf(ww, xv.x, acc.x);
                acc.y = fmaf(ww, xv.y, acc.y);
            }
        }
    }
    if (act) {
        float di = dsi[wv];
        long o = (long)wv * D + c;
        float2 b = *(const float2*)&addB[o];
        *(float2*)&Y[o] = make_float2(fmaf(di, acc.x, b.x), fmaf(di, acc.y, b.y));
    }
}

// ---------------------------------------------------------------- BN stats (sum, sumsq per channel)
__global__ __launch_bounds__(256) void bnstats_kernel(const float* __restrict__ P,
                                                      float* __restrict__ sum,
                                                      float* __restrict__ sq, int N) {
    int c = threadIdx.x & 127;
    int half = threadIdx.x >> 7;
    float s = 0.f, q = 0.f;
    for (long r = blockIdx.x * 2 + half; r < N; r += gridDim.x * 2) {
        float v = P[r * 128 + c];
        s += v;
        q += v * v;
    }
    __shared__ float ls[256], lq[256];
    ls[threadIdx.x] = s;
    lq[threadIdx.x] = q;
    __syncthreads();
    if (threadIdx.x < 128) {
        s = ls[threadIdx.x] + ls[threadIdx.x + 128];
        q = lq[threadIdx.x] + lq[threadIdx.x + 128];
        atomicAdd(&sum[c], s);
        atomicAdd(&sq[c], q);
    }
}

__global__ void bnfinal_kernel(const float* __restrict__ sum, const float* __restrict__ sq,
                               const float* __restrict__ g, const float* __restrict__ be,
                               float* __restrict__ scale, float* __restrict__ shift, float invN) {
    int c = threadIdx.x;  // 128 threads
    float mu = sum[c] * invN;
    float var = sq[c] * invN - mu * mu;
    float sc = g[c] * rsqrtf(var + 1e-5f);
    scale[c] = sc;
    shift[c] = be[c] - mu * sc;
}

// ---------------------------------------------------------------- launch
extern "C" void kernel_launch(void* const* d_in, const int* in_sizes, int n_in,
                              void* d_out, int out_size, void* d_ws, size_t ws_size,
                              hipStream_t stream) {
    const float* feat = (const float*)d_in[0];
    const int* src = (const int*)d_in[1];
    const int* dst = (const int*)d_in[2];
    const float* W0 = (const float*)d_in[3];
    const float* L0 = (const float*)d_in[4];
    const float* W1 = (const float*)d_in[5];
    const float* L1 = (const float*)d_in[6];
    const float* W2 = (const float*)d_in[7];
    const float* L2 = (const float*)d_in[8];
    const float* b2 = (const float*)d_in[9];
    const float* g0 = (const float*)d_in[10];
    const float* be0 = (const float*)d_in[11];
    const float* g1 = (const float*)d_in[12];
    const float* be1 = (const float*)d_in[13];
    float* out = (float*)d_out;

    char* w = (char*)d_ws;
    float* bufA = (float*)(w + 0);            // 51,200,000 B
    float* bufB = (float*)(w + 51200000);     // 51,200,000 B
    int* eidx = (int*)(w + 102400000);        // 6,400,000 B
    float* ewgt = (float*)(w + 108800000);    // 6,400,000 B
    int* outd = (int*)(w + 115200000);        // 400,000 B
    int* ind = (int*)(w + 115600000);         // 400,000 B
    int* cur = (int*)(w + 116000000);         // 400,000 B
    float* dso = (float*)(w + 116400000);     // 400,000 B
    float* dsi = (float*)(w + 116800000);     // 400,000 B
    int* rs = (int*)(w + 117200000);          // 400,000 B
    int* bsum = (int*)(w + 117600000);        // 512 B
    float* bnsum = (float*)(w + 117601024);   // 512 B
    float* bnsq = (float*)(w + 117601536);    // 512 B
    float* scl = (float*)(w + 117602048);     // 512 B
    float* sht = (float*)(w + 117602560);     // 512 B

    float* U2 = bufA;                 // [N][40]
    float* V2 = bufA + 4000000;       // [N][40]

    const int N = NN, E = NE;
    const int NB = (N + 1023) / 1024;  // 98

    // zero: outd, ind, cur (contiguous 1.2 MB)
    hipMemsetAsync(outd, 0, 1200000, stream);

    deg_kernel<<<(E + 255) / 256, 256, 0, stream>>>(src, dst, outd, ind, E);
    ds_kernel<<<(N + 255) / 256, 256, 0, stream>>>(outd, ind, dso, dsi, N);
    scan1_kernel<<<NB, 256, 0, stream>>>(ind, rs, bsum, N);
    scan2_kernel<<<1, 128, 0, stream>>>(bsum, NB);
    scan3_kernel<<<(N + 255) / 256, 256, 0, stream>>>(rs, ind, bsum, N);
    fill_kernel<<<(E + 255) / 256, 256, 0, stream>>>(src, dst, rs, cur, dso, eidx, ewgt, E);

    // ---- layer 0: U=feat@W0 -> bufA, V=feat@L0 -> bufB; P0 = spmm(U)+V -> bufB
    gemm2_kernel<128, false><<<N / 32, 256, 0, stream>>>(feat, W0, L0, nullptr, nullptr, nullptr,
                                                         bufA, bufB, N);
    spmm_kernel<128><<<(N + 3) / 4, 256, 0, stream>>>(bufA, bufB, bufB, eidx, ewgt, rs, ind, dsi, N);
    hipMemsetAsync(bnsum, 0, 1024, stream);
    bnstats_kernel<<<512, 256, 0, stream>>>(bufB, bnsum, bnsq, N);
    bnfinal_kernel<<<1, 128, 0, stream>>>(bnsum, bnsq, g0, be0, scl, sht, 1.0f / N);

    // ---- layer 1: X = bnrelu(P0) on the fly; U -> bufA, V -> bufB (in place); P1 = spmm(U)+V -> bufB
    gemm2_kernel<128, true><<<N / 32, 256, 0, stream>>>(bufB, W1, L1, nullptr, scl, sht,
                                                        bufA, bufB, N);
    spmm_kernel<128><<<(N + 3) / 4, 256, 0, stream>>>(bufA, bufB, bufB, eidx, ewgt, rs, ind, dsi, N);
    hipMemsetAsync(bnsum, 0, 1024, stream);
    bnstats_kernel<<<512, 256, 0, stream>>>(bufB, bnsum, bnsq, N);
    bnfinal_kernel<<<1, 128, 0, stream>>>(bnsum, bnsq, g1, be1, scl, sht, 1.0f / N);

    // ---- layer 2: X = bnrelu(P1) on the fly; U2 = X@W2, V2 = X@L2 + b2; out = spmm(U2)+V2
    gemm2_kernel<40, true><<<N / 32, 256, 0, stream>>>(bufB, W2, L2, b2, scl, sht, U2, V2, N);
    spmm_kernel<40><<<(N + 3) / 4, 256, 0, stream>>>(U2, V2, out, eidx, ewgt, rs, ind, dsi, N);
}

// Round 2
// 845.372 us; speedup vs baseline: 1.1043x; 1.1043x over previous
//
#include <hip/hip_runtime.h>

#define NN 100000
#define NE 1600000

typedef short short8 __attribute__((ext_vector_type(8)));
typedef float f32x4 __attribute__((ext_vector_type(4)));

static __device__ __forceinline__ short f2bf(float f) {
    union { float f; unsigned u; } x;
    x.f = f;
    unsigned r = x.u + 0x7FFFu + ((x.u >> 16) & 1u);
    return (short)(r >> 16);
}
static __device__ __forceinline__ float bf2f(unsigned short b) {
    union { unsigned u; float f; } x;
    x.u = ((unsigned)b) << 16;
    return x.f;
}

// ---------------------------------------------------------------- degrees
__global__ void deg_kernel(const int* __restrict__ src, const int* __restrict__ dst,
                           int* __restrict__ outd, int* __restrict__ ind, int E) {
    int i = blockIdx.x * blockDim.x + threadIdx.x;
    if (i < E) {
        atomicAdd(&outd[src[i]], 1);
        atomicAdd(&ind[dst[i]], 1);
    }
}

__global__ void ds_kernel(const int* __restrict__ outd, const int* __restrict__ ind,
                          float* __restrict__ dso, float* __restrict__ dsi, int N) {
    int i = blockIdx.x * blockDim.x + threadIdx.x;
    if (i < N) {
        int od = outd[i], id = ind[i];
        dso[i] = od > 0 ? rsqrtf((float)od) : 1.0f;
        dsi[i] = id > 0 ? rsqrtf((float)id) : 1.0f;
    }
}

// ---------------------------------------------------------------- scan (row_start)
__global__ __launch_bounds__(256) void scan1_kernel(const int* __restrict__ deg,
                                                    int* __restrict__ rs,
                                                    int* __restrict__ bsum, int N) {
    __shared__ int lds[256];
    int t = threadIdx.x, b = blockIdx.x;
    int base = b * 1024 + t * 4;
    int v0 = 0, v1 = 0, v2 = 0, v3 = 0;
    if (base + 0 < N) v0 = deg[base + 0];
    if (base + 1 < N) v1 = deg[base + 1];
    if (base + 2 < N) v2 = deg[base + 2];
    if (base + 3 < N) v3 = deg[base + 3];
    lds[t] = v0 + v1 + v2 + v3;
    __syncthreads();
    for (int off = 1; off < 256; off <<= 1) {
        int add = (t >= off) ? lds[t - off] : 0;
        __syncthreads();
        lds[t] += add;
        __syncthreads();
    }
    int excl = (t > 0) ? lds[t - 1] : 0;
    if (t == 255) bsum[b] = lds[255];
    int r0 = excl + v0, r1 = r0 + v1, r2 = r1 + v2, r3 = r2 + v3;
    if (base + 0 < N) rs[base + 0] = r0;
    if (base + 1 < N) rs[base + 1] = r1;
    if (base + 2 < N) rs[base + 2] = r2;
    if (base + 3 < N) rs[base + 3] = r3;
}

__global__ void scan2_kernel(int* __restrict__ bsum, int NB) {
    __shared__ int lds[128];
    int t = threadIdx.x;
    lds[t] = (t < NB) ? bsum[t] : 0;
    __syncthreads();
    for (int off = 1; off < 128; off <<= 1) {
        int add = (t >= off) ? lds[t - off] : 0;
        __syncthreads();
        lds[t] += add;
        __syncthreads();
    }
    if (t < NB) bsum[t] = (t > 0) ? lds[t - 1] : 0;
}

__global__ void scan3_kernel(int* __restrict__ rs, const int* __restrict__ deg,
                             const int* __restrict__ bsum, int N) {
    int i = blockIdx.x * blockDim.x + threadIdx.x;
    if (i < N) rs[i] = rs[i] - deg[i] + bsum[i >> 10];
}

// ---------------------------------------------------------------- CSR fill (counting sort by dst)
__global__ void fill_kernel(const int* __restrict__ src, const int* __restrict__ dst,
                            const int* __restrict__ rs, int* __restrict__ cur,
                            int* __restrict__ eidx, int E) {
    int i = blockIdx.x * blockDim.x + threadIdx.x;
    if (i < E) {
        int d = dst[i];
        int slot = atomicAdd(&cur[d], 1);
        eidx[rs[d] + slot] = src[i];
    }
}

// ---------------------------------------------------------------- weight prep: bf16 transpose WT[n][k], pad rows to npad
struct PrepBatch {
    const float* src[6];
    unsigned short* dst[6];
    int nout[6];
    int npad[6];
};
__global__ __launch_bounds__(256) void prep_kernel(PrepBatch pb) {
    int m = blockIdx.y;
    int npad = pb.npad[m], nout = pb.nout[m];
    int i = blockIdx.x * 256 + threadIdx.x;
    if (i < 128 * npad) {
        int k = i / npad, n = i - k * npad;
        float v = (n < nout) ? pb.src[m][k * nout + n] : 0.0f;
        pb.dst[m][n * 128 + k] = (unsigned short)f2bf(v);
    }
}

// ---------------------------------------------------------------- MFMA dual GEMM
// U[row][c] = dso[row] * (X@W)[row][c]  (bf16 out),  V = X@L (+bias) (f32 out)
// X: [N][128] f32 (optional BN+ReLU on the fly). WT/LT: [npad][128] bf16 transposed.
// Block: 256 thr = 4 waves; BM=64 (16 rows/wave). NT tiles of 16 cols.
template <int NT, bool BN, bool BIAS>
__global__ __launch_bounds__(256) void gemm_mfma_kernel(
    const float* __restrict__ X, const unsigned short* __restrict__ WT,
    const unsigned short* __restrict__ LT, const float* __restrict__ bias,
    const float* __restrict__ scale, const float* __restrict__ shift,
    const float* __restrict__ dso, unsigned short* __restrict__ U, float* __restrict__ V,
    int N, int mout) {
    const int tid = threadIdx.x;
    const int w = tid >> 6, l = tid & 63;
    const int lr = l & 15, kg = l >> 4;
    const long row = (long)blockIdx.x * 64 + w * 16 + lr;
    f32x4 accU[NT];
    f32x4 accV[NT];
#pragma unroll
    for (int t = 0; t < NT; ++t) {
        accU[t] = (f32x4)(0.0f);
        accV[t] = (f32x4)(0.0f);
    }

#pragma unroll
    for (int kc = 0; kc < 4; ++kc) {
        const int kb = kc * 32 + kg * 8;
        // A fragment: X[row][kb..kb+7] with optional BN+ReLU, cvt to bf16
        short8 av;
        if (row < N) {
            float4 x0 = *(const float4*)&X[row * 128 + kb];
            float4 x1 = *(const float4*)&X[row * 128 + kb + 4];
            float xs[8] = {x0.x, x0.y, x0.z, x0.w, x1.x, x1.y, x1.z, x1.w};
            if (BN) {
                float4 s0 = *(const float4*)&scale[kb];
                float4 s1 = *(const float4*)&scale[kb + 4];
                float4 h0 = *(const float4*)&shift[kb];
                float4 h1 = *(const float4*)&shift[kb + 4];
                float ss[8] = {s0.x, s0.y, s0.z, s0.w, s1.x, s1.y, s1.z, s1.w};
                float hh[8] = {h0.x, h0.y, h0.z, h0.w, h1.x, h1.y, h1.z, h1.w};
#pragma unroll
                for (int j = 0; j < 8; ++j) xs[j] = fmaxf(fmaf(xs[j], ss[j], hh[j]), 0.0f);
            }
#pragma unroll
            for (int j = 0; j < 8; ++j) av[j] = f2bf(xs[j]);
        } else {
#pragma unroll
            for (int j = 0; j < 8; ++j) av[j] = 0;
        }
#pragma unroll
        for (int t = 0; t < NT; ++t) {
            short8 bw = *(const short8*)&WT[(t * 16 + lr) * 128 + kb];
            short8 bl = *(const short8*)&LT[(t * 16 + lr) * 128 + kb];
            accU[t] = __builtin_amdgcn_mfma_f32_16x16x32_bf16(av, bw, accU[t], 0, 0, 0);
            accV[t] = __builtin_amdgcn_mfma_f32_16x16x32_bf16(av, bl, accV[t], 0, 0, 0);
        }
    }

    // epilogue: C/D layout col = lane&15, row = (lane>>4)*4 + reg
    const long rr0 = (long)blockIdx.x * 64 + w * 16 + kg * 4;
#pragma unroll
    for (int t = 0; t < NT; ++t) {
        const int c = t * 16 + lr;
        if (c < mout) {
#pragma unroll
            for (int r = 0; r < 4; ++r) {
                const long rr = rr0 + r;
                if (rr < N) {
                    float u = accU[t][r] * dso[rr];
                    U[rr * mout + c] = (unsigned short)f2bf(u);
                    float v = accV[t][r];
                    if (BIAS) v += bias[c];
                    V[rr * mout + c] = v;
                }
            }
        }
    }
}

// ---------------------------------------------------------------- SpMM (bf16 gather, weights pre-folded)
// Y[n][c] = dsi[n] * sum_e Uin[eidx_e][c] + addB[n][c]   (addB may alias Y)
template <int D>
__global__ __launch_bounds__(256) void spmm_bf16_kernel(
    const unsigned short* __restrict__ Uin, const float* __restrict__ addB,
    float* __restrict__ Y, const int* __restrict__ eidx, const int* __restrict__ rs,
    const int* __restrict__ deg, const float* __restrict__ dsi, int N) {
    int wv = blockIdx.x * 4 + (threadIdx.x >> 6);
    int lane = threadIdx.x & 63;
    if (wv >= N) return;
    int start = rs[wv];
    int dg = deg[wv];
    if (D == 128) {
        const int c = lane * 2;
        float ax = 0.f, ay = 0.f;
        for (int j0 = 0; j0 < dg; j0 += 64) {
            int m = min(64, dg - j0);
            int sidx = 0;
            if (lane < m) sidx = eidx[start + j0 + lane];
            for (int j = 0; j < m; ++j) {
                int s = __shfl(sidx, j);
                unsigned p = *(const unsigned*)&Uin[(long)s * 128 + c];
                ax += bf2f((unsigned short)(p & 0xFFFFu));
                ay += bf2f((unsigned short)(p >> 16));
            }
        }
        float di = dsi[wv];
        long o = (long)wv * 128 + c;
        float2 b = *(const float2*)&addB[o];
        *(float2*)&Y[o] = make_float2(fmaf(di, ax, b.x), fmaf(di, ay, b.y));
    } else {
        const bool act = lane < D;
        float acc = 0.f;
        for (int j0 = 0; j0 < dg; j0 += 64) {
            int m = min(64, dg - j0);
            int sidx = 0;
            if (lane < m) sidx = eidx[start + j0 + lane];
            for (int j = 0; j < m; ++j) {
                int s = __shfl(sidx, j);
                if (act) acc += bf2f(Uin[(long)s * D + lane]);
            }
        }
        if (act) {
            long o = (long)wv * D + lane;
            Y[o] = fmaf(dsi[wv], acc, addB[o]);
        }
    }
}

// ---------------------------------------------------------------- BN stats (sum, sumsq per channel)
__global__ __launch_bounds__(256) void bnstats_kernel(const float* __restrict__ P,
                                                      float* __restrict__ sum,
                                                      float* __restrict__ sq, int N) {
    int c = threadIdx.x & 127;
    int half = threadIdx.x >> 7;
    float s = 0.f, q = 0.f;
    for (long r = blockIdx.x * 2 + half; r < N; r += gridDim.x * 2) {
        float v = P[r * 128 + c];
        s += v;
        q += v * v;
    }
    __shared__ float ls[256], lq[256];
    ls[threadIdx.x] = s;
    lq[threadIdx.x] = q;
    __syncthreads();
    if (threadIdx.x < 128) {
        s = ls[threadIdx.x] + ls[threadIdx.x + 128];
        q = lq[threadIdx.x] + lq[threadIdx.x + 128];
        atomicAdd(&sum[c], s);
        atomicAdd(&sq[c], q);
    }
}

__global__ void bnfinal_kernel(const float* __restrict__ sum, const float* __restrict__ sq,
                               const float* __restrict__ g, const float* __restrict__ be,
                               float* __restrict__ scale, float* __restrict__ shift, float invN) {
    int c = threadIdx.x;  // 128 threads
    float mu = sum[c] * invN;
    float var = sq[c] * invN - mu * mu;
    float sc = g[c] * rsqrtf(var + 1e-5f);
    scale[c] = sc;
    shift[c] = be[c] - mu * sc;
}

// ---------------------------------------------------------------- launch
extern "C" void kernel_launch(void* const* d_in, const int* in_sizes, int n_in,
                              void* d_out, int out_size, void* d_ws, size_t ws_size,
                              hipStream_t stream) {
    const float* feat = (const float*)d_in[0];
    const int* src = (const int*)d_in[1];
    const int* dst = (const int*)d_in[2];
    const float* W0 = (const float*)d_in[3];
    const float* L0 = (const float*)d_in[4];
    const float* W1 = (const float*)d_in[5];
    const float* L1 = (const float*)d_in[6];
    const float* W2 = (const float*)d_in[7];
    const float* L2 = (const float*)d_in[8];
    const float* b2 = (const float*)d_in[9];
    const float* g0 = (const float*)d_in[10];
    const float* be0 = (const float*)d_in[11];
    const float* g1 = (const float*)d_in[12];
    const float* be1 = (const float*)d_in[13];
    float* out = (float*)d_out;

    char* w = (char*)d_ws;
    float* bufP = (float*)(w + 0);                    // 51,200,000 B  (X / P / V in-place)
    unsigned short* bufU = (unsigned short*)(w + 51200000);  // 25,600,000 B (bf16 U)
    float* V2 = (float*)(w + 76800000);               // 16,000,000 B (layer2 V f32)
    int* eidx = (int*)(w + 92800000);                 // 6,400,000 B
    int* outd = (int*)(w + 99200000);                 // 400,000 B
    int* ind = (int*)(w + 99600000);                  // 400,000 B
    int* cur = (int*)(w + 100000000);                 // 400,000 B
    float* dso = (float*)(w + 100400000);             // 400,000 B
    float* dsi = (float*)(w + 100800000);             // 400,000 B
    int* rs = (int*)(w + 101200000);                  // 400,000 B
    int* bsum = (int*)(w + 101600000);                // 512 B
    float* bnsum = (float*)(w + 101600512);           // 512 B
    float* bnsq = (float*)(w + 101601024);            // 512 B
    float* scl = (float*)(w + 101601536);             // 512 B
    float* sht = (float*)(w + 101602048);             // 512 B
    unsigned short* W0T = (unsigned short*)(w + 101602560);  // 32768 B each (128x128 bf16)
    unsigned short* L0T = (unsigned short*)(w + 101635328);
    unsigned short* W1T = (unsigned short*)(w + 101668096);
    unsigned short* L1T = (unsigned short*)(w + 101700864);
    unsigned short* W2T = (unsigned short*)(w + 101733632);  // 48x128 bf16 = 12288 B
    unsigned short* L2T = (unsigned short*)(w + 101745920);

    const int N = NN, E = NE;
    const int NB = (N + 1023) / 1024;  // 98
    const int GB = (N + 63) / 64;      // 1563 gemm blocks

    // zero: outd, ind, cur (contiguous 1.2 MB)
    hipMemsetAsync(outd, 0, 1200000, stream);

    // weight prep (independent of graph build)
    PrepBatch pb;
    pb.src[0] = W0; pb.dst[0] = W0T; pb.nout[0] = 128; pb.npad[0] = 128;
    pb.src[1] = L0; pb.dst[1] = L0T; pb.nout[1] = 128; pb.npad[1] = 128;
    pb.src[2] = W1; pb.dst[2] = W1T; pb.nout[2] = 128; pb.npad[2] = 128;
    pb.src[3] = L1; pb.dst[3] = L1T; pb.nout[3] = 128; pb.npad[3] = 128;
    pb.src[4] = W2; pb.dst[4] = W2T; pb.nout[4] = 40;  pb.npad[4] = 48;
    pb.src[5] = L2; pb.dst[5] = L2T; pb.nout[5] = 40;  pb.npad[5] = 48;
    prep_kernel<<<dim3(64, 6), 256, 0, stream>>>(pb);

    deg_kernel<<<(E + 255) / 256, 256, 0, stream>>>(src, dst, outd, ind, E);
    ds_kernel<<<(N + 255) / 256, 256, 0, stream>>>(outd, ind, dso, dsi, N);
    scan1_kernel<<<NB, 256, 0, stream>>>(ind, rs, bsum, N);
    scan2_kernel<<<1, 128, 0, stream>>>(bsum, NB);
    scan3_kernel<<<(N + 255) / 256, 256, 0, stream>>>(rs, ind, bsum, N);
    fill_kernel<<<(E + 255) / 256, 256, 0, stream>>>(src, dst, rs, cur, eidx, E);

    // ---- layer 0: U0 = dso*(feat@W0) bf16 -> bufU, V0 = feat@L0 -> bufP; P0 = spmm(U0)+V0 -> bufP
    gemm_mfma_kernel<8, false, false><<<GB, 256, 0, stream>>>(
        feat, W0T, L0T, nullptr, nullptr, nullptr, dso, bufU, bufP, N, 128);
    spmm_bf16_kernel<128><<<(N + 3) / 4, 256, 0, stream>>>(bufU, bufP, bufP, eidx, rs, ind, dsi, N);
    hipMemsetAsync(bnsum, 0, 1024, stream);
    bnstats_kernel<<<512, 256, 0, stream>>>(bufP, bnsum, bnsq, N);
    bnfinal_kernel<<<1, 128, 0, stream>>>(bnsum, bnsq, g0, be0, scl, sht, 1.0f / N);

    // ---- layer 1: X = bnrelu(P0) on the fly
    gemm_mfma_kernel<8, true, false><<<GB, 256, 0, stream>>>(
        bufP, W1T, L1T, nullptr, scl, sht, dso, bufU, bufP, N, 128);
    spmm_bf16_kernel<128><<<(N + 3) / 4, 256, 0, stream>>>(bufU, bufP, bufP, eidx, rs, ind, dsi, N);
    hipMemsetAsync(bnsum, 0, 1024, stream);
    bnstats_kernel<<<512, 256, 0, stream>>>(bufP, bnsum, bnsq, N);
    bnfinal_kernel<<<1, 128, 0, stream>>>(bnsum, bnsq, g1, be1, scl, sht, 1.0f / N);

    // ---- layer 2: U2 = dso*(X@W2) bf16 (pitch 40) -> bufU, V2 = X@L2 + b2 -> V2
    gemm_mfma_kernel<3, true, true><<<GB, 256, 0, stream>>>(
        bufP, W2T, L2T, b2, scl, sht, dso, bufU, V2, N, 40);
    spmm_bf16_kernel<40><<<(N + 3) / 4, 256, 0, stream>>>(bufU, V2, out, eidx, rs, ind, dsi, N);
}

// Round 3
// 733.120 us; speedup vs baseline: 1.2734x; 1.1531x over previous
//
#include <hip/hip_runtime.h>

#define NN 100000
#define NE 1600000
#define NCHUNK 32
#define CHSZ (NE / NCHUNK)   // 50000 edges per chunk
#define NRANGE 8
#define RSZ (NN / NRANGE)    // 12500 nodes per range

typedef short short8 __attribute__((ext_vector_type(8)));
typedef float f32x4 __attribute__((ext_vector_type(4)));

static __device__ __forceinline__ short f2bf(float f) {
    union { float f; unsigned u; } x;
    x.f = f;
    unsigned r = x.u + 0x7FFFu + ((x.u >> 16) & 1u);
    return (short)(r >> 16);
}
static __device__ __forceinline__ float bf2f(unsigned short b) {
    union { unsigned u; float f; } x;
    x.u = ((unsigned)b) << 16;
    return x.f;
}

// ---------------------------------------------------------------- per-chunk histograms (no global atomics)
// grid: (chunk, range, z)  z=0: src -> Hout, z=1: dst -> Hin. Plain stores of LDS hist.
__global__ __launch_bounds__(256) void hist_kernel(const int* __restrict__ src,
                                                   const int* __restrict__ dst,
                                                   int* __restrict__ Hout,
                                                   int* __restrict__ Hin) {
    __shared__ int hist[RSZ];
    const int c = blockIdx.x, r = blockIdx.y, z = blockIdx.z;
    const int r0 = r * RSZ;
    for (int j = threadIdx.x; j < RSZ; j += 256) hist[j] = 0;
    __syncthreads();
    const int4* p = (const int4*)((z ? dst : src) + c * CHSZ);
    for (int i = threadIdx.x; i < CHSZ / 4; i += 256) {
        int4 v = p[i];
        unsigned a;
        a = (unsigned)(v.x - r0); if (a < RSZ) atomicAdd(&hist[a], 1);
        a = (unsigned)(v.y - r0); if (a < RSZ) atomicAdd(&hist[a], 1);
        a = (unsigned)(v.z - r0); if (a < RSZ) atomicAdd(&hist[a], 1);
        a = (unsigned)(v.w - r0); if (a < RSZ) atomicAdd(&hist[a], 1);
    }
    __syncthreads();
    int* H = (z ? Hin : Hout) + c * NN + r0;
    for (int j = threadIdx.x; j < RSZ; j += 256) H[j] = hist[j];
}

// ---------------------------------------------------------------- reduce Hout -> dso; exclusive-scan Hin over chunks -> ind, dsi
__global__ __launch_bounds__(256) void redscan_kernel(const int* __restrict__ Hout,
                                                      int* __restrict__ Hin,
                                                      int* __restrict__ ind,
                                                      float* __restrict__ dso,
                                                      float* __restrict__ dsi) {
    int d = blockIdx.x * 256 + threadIdx.x;
    if (d >= NN) return;
    int so = 0;
#pragma unroll
    for (int c = 0; c < NCHUNK; ++c) so += Hout[c * NN + d];
    dso[d] = so > 0 ? rsqrtf((float)so) : 1.0f;
    int run = 0;
#pragma unroll
    for (int c = 0; c < NCHUNK; ++c) {
        int t = Hin[c * NN + d];
        Hin[c * NN + d] = run;
        run += t;
    }
    ind[d] = run;
    dsi[d] = run > 0 ? rsqrtf((float)run) : 1.0f;
}

// ---------------------------------------------------------------- scan (row_start)
__global__ __launch_bounds__(256) void scan1_kernel(const int* __restrict__ deg,
                                                    int* __restrict__ rs,
                                                    int* __restrict__ bsum, int N) {
    __shared__ int lds[256];
    int t = threadIdx.x, b = blockIdx.x;
    int base = b * 1024 + t * 4;
    int v0 = 0, v1 = 0, v2 = 0, v3 = 0;
    if (base + 0 < N) v0 = deg[base + 0];
    if (base + 1 < N) v1 = deg[base + 1];
    if (base + 2 < N) v2 = deg[base + 2];
    if (base + 3 < N) v3 = deg[base + 3];
    lds[t] = v0 + v1 + v2 + v3;
    __syncthreads();
    for (int off = 1; off < 256; off <<= 1) {
        int add = (t >= off) ? lds[t - off] : 0;
        __syncthreads();
        lds[t] += add;
        __syncthreads();
    }
    int excl = (t > 0) ? lds[t - 1] : 0;
    if (t == 255) bsum[b] = lds[255];
    int r0 = excl + v0, r1 = r0 + v1, r2 = r1 + v2, r3 = r2 + v3;
    if (base + 0 < N) rs[base + 0] = r0;
    if (base + 1 < N) rs[base + 1] = r1;
    if (base + 2 < N) rs[base + 2] = r2;
    if (base + 3 < N) rs[base + 3] = r3;
}

__global__ void scan2_kernel(int* __restrict__ bsum, int NB) {
    __shared__ int lds[128];
    int t = threadIdx.x;
    lds[t] = (t < NB) ? bsum[t] : 0;
    __syncthreads();
    for (int off = 1; off < 128; off <<= 1) {
        int add = (t >= off) ? lds[t - off] : 0;
        __syncthreads();
        lds[t] += add;
        __syncthreads();
    }
    if (t < NB) bsum[t] = (t > 0) ? lds[t - 1] : 0;
}

// scan3: rs = exclusive row start; also fold rs into every Hin[c][i] (global slot bases)
__global__ void scan3_kernel(int* __restrict__ rs, const int* __restrict__ deg,
                             const int* __restrict__ bsum, int* __restrict__ Hin, int N) {
    int i = blockIdx.x * blockDim.x + threadIdx.x;
    if (i < N) {
        int v = rs[i] - deg[i] + bsum[i >> 10];
        rs[i] = v;
#pragma unroll
        for (int c = 0; c < NCHUNK; ++c) Hin[c * NN + i] += v;
    }
}

// ---------------------------------------------------------------- CSR fill (counting sort, no global atomics)
// grid: (chunk, range). slot = Hin[c][d] + LDS-local rank.
__global__ __launch_bounds__(256) void fill_kernel(const int* __restrict__ src,
                                                   const int* __restrict__ dst,
                                                   const int* __restrict__ Hin,
                                                   int* __restrict__ eidx) {
    __shared__ int cnt[RSZ];
    const int c = blockIdx.x, r = blockIdx.y;
    const int r0 = r * RSZ;
    for (int j = threadIdx.x; j < RSZ; j += 256) cnt[j] = 0;
    __syncthreads();
    const int4* ps = (const int4*)(src + c * CHSZ);
    const int4* pd = (const int4*)(dst + c * CHSZ);
    const int* Hc = Hin + c * NN;
    for (int i = threadIdx.x; i < CHSZ / 4; i += 256) {
        int4 s4 = ps[i];
        int4 d4 = pd[i];
        int ss[4] = {s4.x, s4.y, s4.z, s4.w};
        int dd[4] = {d4.x, d4.y, d4.z, d4.w};
#pragma unroll
        for (int k = 0; k < 4; ++k) {
            unsigned a = (unsigned)(dd[k] - r0);
            if (a < RSZ) {
                int local = atomicAdd(&cnt[a], 1);
                eidx[Hc[dd[k]] + local] = ss[k];
            }
        }
    }
}

// ---------------------------------------------------------------- weight prep: bf16 transpose WT[n][k], pad rows to npad
struct PrepBatch {
    const float* src[6];
    unsigned short* dst[6];
    int nout[6];
    int npad[6];
};
__global__ __launch_bounds__(256) void prep_kernel(PrepBatch pb) {
    int m = blockIdx.y;
    int npad = pb.npad[m], nout = pb.nout[m];
    int i = blockIdx.x * 256 + threadIdx.x;
    if (i < 128 * npad) {
        int k = i / npad, n = i - k * npad;
        float v = (n < nout) ? pb.src[m][k * nout + n] : 0.0f;
        pb.dst[m][n * 128 + k] = (unsigned short)f2bf(v);
    }
}

// ---------------------------------------------------------------- MFMA dual GEMM
// U[row][c] = dso[row] * (X@W)[row][c]  (bf16 out),  V = X@L (+bias) (f32 out)
template <int NT, bool BN, bool BIAS>
__global__ __launch_bounds__(256) void gemm_mfma_kernel(
    const float* __restrict__ X, const unsigned short* __restrict__ WT,
    const unsigned short* __restrict__ LT, const float* __restrict__ bias,
    const float* __restrict__ scale, const float* __restrict__ shift,
    const float* __restrict__ dso, unsigned short* __restrict__ U, float* __restrict__ V,
    int N, int mout) {
    const int tid = threadIdx.x;
    const int w = tid >> 6, l = tid & 63;
    const int lr = l & 15, kg = l >> 4;
    const long row = (long)blockIdx.x * 64 + w * 16 + lr;
    f32x4 accU[NT];
    f32x4 accV[NT];
#pragma unroll
    for (int t = 0; t < NT; ++t) {
        accU[t] = (f32x4)(0.0f);
        accV[t] = (f32x4)(0.0f);
    }

#pragma unroll
    for (int kc = 0; kc < 4; ++kc) {
        const int kb = kc * 32 + kg * 8;
        short8 av;
        if (row < N) {
            float4 x0 = *(const float4*)&X[row * 128 + kb];
            float4 x1 = *(const float4*)&X[row * 128 + kb + 4];
            float xs[8] = {x0.x, x0.y, x0.z, x0.w, x1.x, x1.y, x1.z, x1.w};
            if (BN) {
                float4 s0 = *(const float4*)&scale[kb];
                float4 s1 = *(const float4*)&scale[kb + 4];
                float4 h0 = *(const float4*)&shift[kb];
                float4 h1 = *(const float4*)&shift[kb + 4];
                float ss[8] = {s0.x, s0.y, s0.z, s0.w, s1.x, s1.y, s1.z, s1.w};
                float hh[8] = {h0.x, h0.y, h0.z, h0.w, h1.x, h1.y, h1.z, h1.w};
#pragma unroll
                for (int j = 0; j < 8; ++j) xs[j] = fmaxf(fmaf(xs[j], ss[j], hh[j]), 0.0f);
            }
#pragma unroll
            for (int j = 0; j < 8; ++j) av[j] = f2bf(xs[j]);
        } else {
#pragma unroll
            for (int j = 0; j < 8; ++j) av[j] = 0;
        }
#pragma unroll
        for (int t = 0; t < NT; ++t) {
            short8 bw = *(const short8*)&WT[(t * 16 + lr) * 128 + kb];
            short8 bl = *(const short8*)&LT[(t * 16 + lr) * 128 + kb];
            accU[t] = __builtin_amdgcn_mfma_f32_16x16x32_bf16(av, bw, accU[t], 0, 0, 0);
            accV[t] = __builtin_amdgcn_mfma_f32_16x16x32_bf16(av, bl, accV[t], 0, 0, 0);
        }
    }

    const long rr0 = (long)blockIdx.x * 64 + w * 16 + kg * 4;
#pragma unroll
    for (int t = 0; t < NT; ++t) {
        const int c = t * 16 + lr;
        if (c < mout) {
#pragma unroll
            for (int r = 0; r < 4; ++r) {
                const long rr = rr0 + r;
                if (rr < N) {
                    float u = accU[t][r] * dso[rr];
                    U[rr * mout + c] = (unsigned short)f2bf(u);
                    float v = accV[t][r];
                    if (BIAS) v += bias[c];
                    V[rr * mout + c] = v;
                }
            }
        }
    }
}

// ---------------------------------------------------------------- SpMM (bf16 gather, weights pre-folded)
template <int D>
__global__ __launch_bounds__(256) void spmm_bf16_kernel(
    const unsigned short* __restrict__ Uin, const float* __restrict__ addB,
    float* __restrict__ Y, const int* __restrict__ eidx, const int* __restrict__ rs,
    const int* __restrict__ deg, const float* __restrict__ dsi, int N) {
    int wv = blockIdx.x * 4 + (threadIdx.x >> 6);
    int lane = threadIdx.x & 63;
    if (wv >= N) return;
    int start = rs[wv];
    int dg = deg[wv];
    if (D == 128) {
        const int c = lane * 2;
        float ax = 0.f, ay = 0.f;
        for (int j0 = 0; j0 < dg; j0 += 64) {
            int m = min(64, dg - j0);
            int sidx = 0;
            if (lane < m) sidx = eidx[start + j0 + lane];
            for (int j = 0; j < m; ++j) {
                int s = __shfl(sidx, j);
                unsigned p = *(const unsigned*)&Uin[(long)s * 128 + c];
                ax += bf2f((unsigned short)(p & 0xFFFFu));
                ay += bf2f((unsigned short)(p >> 16));
            }
        }
        float di = dsi[wv];
        long o = (long)wv * 128 + c;
        float2 b = *(const float2*)&addB[o];
        *(float2*)&Y[o] = make_float2(fmaf(di, ax, b.x), fmaf(di, ay, b.y));
    } else {
        const bool act = lane < D;
        float acc = 0.f;
        for (int j0 = 0; j0 < dg; j0 += 64) {
            int m = min(64, dg - j0);
            int sidx = 0;
            if (lane < m) sidx = eidx[start + j0 + lane];
            for (int j = 0; j < m; ++j) {
                int s = __shfl(sidx, j);
                if (act) acc += bf2f(Uin[(long)s * D + lane]);
            }
        }
        if (act) {
            long o = (long)wv * D + lane;
            Y[o] = fmaf(dsi[wv], acc, addB[o]);
        }
    }
}

// ---------------------------------------------------------------- BN stats (sum, sumsq per channel)
__global__ __launch_bounds__(256) void bnstats_kernel(const float* __restrict__ P,
                                                      float* __restrict__ sum,
                                                      float* __restrict__ sq, int N) {
    int c = threadIdx.x & 127;
    int half = threadIdx.x >> 7;
    float s = 0.f, q = 0.f;
    for (long r = blockIdx.x * 2 + half; r < N; r += gridDim.x * 2) {
        float v = P[r * 128 + c];
        s += v;
        q += v * v;
    }
    __shared__ float ls[256], lq[256];
    ls[threadIdx.x] = s;
    lq[threadIdx.x] = q;
    __syncthreads();
    if (threadIdx.x < 128) {
        s = ls[threadIdx.x] + ls[threadIdx.x + 128];
        q = lq[threadIdx.x] + lq[threadIdx.x + 128];
        atomicAdd(&sum[c], s);
        atomicAdd(&sq[c], q);
    }
}

__global__ void bnfinal_kernel(const float* __restrict__ sum, const float* __restrict__ sq,
                               const float* __restrict__ g, const float* __restrict__ be,
                               float* __restrict__ scale, float* __restrict__ shift, float invN) {
    int c = threadIdx.x;  // 128 threads
    float mu = sum[c] * invN;
    float var = sq[c] * invN - mu * mu;
    float sc = g[c] * rsqrtf(var + 1e-5f);
    scale[c] = sc;
    shift[c] = be[c] - mu * sc;
}

// ---------------------------------------------------------------- launch
extern "C" void kernel_launch(void* const* d_in, const int* in_sizes, int n_in,
                              void* d_out, int out_size, void* d_ws, size_t ws_size,
                              hipStream_t stream) {
    const float* feat = (const float*)d_in[0];
    const int* src = (const int*)d_in[1];
    const int* dst = (const int*)d_in[2];
    const float* W0 = (const float*)d_in[3];
    const float* L0 = (const float*)d_in[4];
    const float* W1 = (const float*)d_in[5];
    const float* L1 = (const float*)d_in[6];
    const float* W2 = (const float*)d_in[7];
    const float* L2 = (const float*)d_in[8];
    const float* b2 = (const float*)d_in[9];
    const float* g0 = (const float*)d_in[10];
    const float* be0 = (const float*)d_in[11];
    const float* g1 = (const float*)d_in[12];
    const float* be1 = (const float*)d_in[13];
    float* out = (float*)d_out;

    char* w = (char*)d_ws;
    float* bufP = (float*)(w + 0);                           // 51,200,000 B (X / P / V in-place)
    unsigned short* bufU = (unsigned short*)(w + 51200000);  // 25,600,000 B (bf16 U)
    float* V2 = (float*)(w + 76800000);                      // 16,000,000 B (layer2 V f32)
    int* eidx = (int*)(w + 92800000);                        // 6,400,000 B
    int* ind = (int*)(w + 99200000);                         // 400,000 B
    float* dso = (float*)(w + 99600000);                     // 400,000 B
    float* dsi = (float*)(w + 100000000);                    // 400,000 B
    int* rs = (int*)(w + 100400000);                         // 400,000 B
    int* bsum = (int*)(w + 100800000);                       // 512 B
    float* bnsum = (float*)(w + 100801024);                  // 512 B
    float* bnsq = (float*)(w + 100801536);                   // 512 B
    float* scl = (float*)(w + 100802048);                    // 512 B
    float* sht = (float*)(w + 100802560);                    // 512 B
    unsigned short* W0T = (unsigned short*)(w + 100803072);  // 32768 B each (128x128 bf16)
    unsigned short* L0T = (unsigned short*)(w + 100835840);
    unsigned short* W1T = (unsigned short*)(w + 100868608);
    unsigned short* L1T = (unsigned short*)(w + 100901376);
    unsigned short* W2T = (unsigned short*)(w + 100934144);  // 48x128 bf16 = 12288 B
    unsigned short* L2T = (unsigned short*)(w + 100946432);

    // H matrices alias later-written buffers (dead by the time those are written):
    int* Hout = (int*)bufU;  // 12.8 MB <= 25.6 MB; dead after redscan (before gemm0 writes bufU)
    int* Hin = (int*)V2;     // 12.8 MB <= 16 MB; dead after fill (before gemm2 writes V2)

    const int N = NN, E = NE;
    const int NB = (N + 1023) / 1024;  // 98
    const int GB = (N + 63) / 64;      // 1563 gemm blocks

    // weight prep (independent of graph build)
    PrepBatch pb;
    pb.src[0] = W0; pb.dst[0] = W0T; pb.nout[0] = 128; pb.npad[0] = 128;
    pb.src[1] = L0; pb.dst[1] = L0T; pb.nout[1] = 128; pb.npad[1] = 128;
    pb.src[2] = W1; pb.dst[2] = W1T; pb.nout[2] = 128; pb.npad[2] = 128;
    pb.src[3] = L1; pb.dst[3] = L1T; pb.nout[3] = 128; pb.npad[3] = 128;
    pb.src[4] = W2; pb.dst[4] = W2T; pb.nout[4] = 40;  pb.npad[4] = 48;
    pb.src[5] = L2; pb.dst[5] = L2T; pb.nout[5] = 40;  pb.npad[5] = 48;
    prep_kernel<<<dim3(64, 6), 256, 0, stream>>>(pb);

    // graph build (no global atomics)
    hist_kernel<<<dim3(NCHUNK, NRANGE, 2), 256, 0, stream>>>(src, dst, Hout, Hin);
    redscan_kernel<<<(N + 255) / 256, 256, 0, stream>>>(Hout, Hin, ind, dso, dsi);
    scan1_kernel<<<NB, 256, 0, stream>>>(ind, rs, bsum, N);
    scan2_kernel<<<1, 128, 0, stream>>>(bsum, NB);
    scan3_kernel<<<(N + 255) / 256, 256, 0, stream>>>(rs, ind, bsum, Hin, N);
    fill_kernel<<<dim3(NCHUNK, NRANGE), 256, 0, stream>>>(src, dst, Hin, eidx);

    // ---- layer 0: U0 = dso*(feat@W0) bf16 -> bufU, V0 = feat@L0 -> bufP; P0 = spmm(U0)+V0 -> bufP
    gemm_mfma_kernel<8, false, false><<<GB, 256, 0, stream>>>(
        feat, W0T, L0T, nullptr, nullptr, nullptr, dso, bufU, bufP, N, 128);
    spmm_bf16_kernel<128><<<(N + 3) / 4, 256, 0, stream>>>(bufU, bufP, bufP, eidx, rs, ind, dsi, N);
    hipMemsetAsync(bnsum, 0, 1024, stream);
    bnstats_kernel<<<512, 256, 0, stream>>>(bufP, bnsum, bnsq, N);
    bnfinal_kernel<<<1, 128, 0, stream>>>(bnsum, bnsq, g0, be0, scl, sht, 1.0f / N);

    // ---- layer 1: X = bnrelu(P0) on the fly
    gemm_mfma_kernel<8, true, false><<<GB, 256, 0, stream>>>(
        bufP, W1T, L1T, nullptr, scl, sht, dso, bufU, bufP, N, 128);
    spmm_bf16_kernel<128><<<(N + 3) / 4, 256, 0, stream>>>(bufU, bufP, bufP, eidx, rs, ind, dsi, N);
    hipMemsetAsync(bnsum, 0, 1024, stream);
    bnstats_kernel<<<512, 256, 0, stream>>>(bufP, bnsum, bnsq, N);
    bnfinal_kernel<<<1, 128, 0, stream>>>(bnsum, bnsq, g1, be1, scl, sht, 1.0f / N);

    // ---- layer 2: U2 = dso*(X@W2) bf16 (pitch 40) -> bufU, V2 = X@L2 + b2 -> V2
    gemm_mfma_kernel<3, true, true><<<GB, 256, 0, stream>>>(
        bufP, W2T, L2T, b2, scl, sht, dso, bufU, V2, N, 40);
    spmm_bf16_kernel<40><<<(N + 3) / 4, 256, 0, stream>>>(bufU, V2, out, eidx, rs, ind, dsi, N);
}

// Round 5
// 600.668 us; speedup vs baseline: 1.5541x; 1.2205x over previous
//
#include <hip/hip_runtime.h>

#define NN 100000
#define NE 1600000
#define NCHUNK 32
#define CHSZ (NE / NCHUNK)   // 50000 edges per chunk
#define NRANGE 8
#define RSZ (NN / NRANGE)    // 12500 nodes per range

typedef short short8 __attribute__((ext_vector_type(8)));
typedef float f32x4 __attribute__((ext_vector_type(4)));

static __device__ __forceinline__ short f2bf(float f) {
    union { float f; unsigned u; } x;
    x.f = f;
    unsigned r = x.u + 0x7FFFu + ((x.u >> 16) & 1u);
    return (short)(r >> 16);
}

// ---------------------------------------------------------------- per-chunk histograms (no global atomics)
__global__ __launch_bounds__(256) void hist_kernel(const int* __restrict__ src,
                                                   const int* __restrict__ dst,
                                                   int* __restrict__ Hout,
                                                   int* __restrict__ Hin) {
    __shared__ int hist[RSZ];
    const int c = blockIdx.x, r = blockIdx.y, z = blockIdx.z;
    const int r0 = r * RSZ;
    for (int j = threadIdx.x; j < RSZ; j += 256) hist[j] = 0;
    __syncthreads();
    const int4* p = (const int4*)((z ? dst : src) + c * CHSZ);
    for (int i = threadIdx.x; i < CHSZ / 4; i += 256) {
        int4 v = p[i];
        unsigned a;
        a = (unsigned)(v.x - r0); if (a < RSZ) atomicAdd(&hist[a], 1);
        a = (unsigned)(v.y - r0); if (a < RSZ) atomicAdd(&hist[a], 1);
        a = (unsigned)(v.z - r0); if (a < RSZ) atomicAdd(&hist[a], 1);
        a = (unsigned)(v.w - r0); if (a < RSZ) atomicAdd(&hist[a], 1);
    }
    __syncthreads();
    int* H = (z ? Hin : Hout) + c * NN + r0;
    for (int j = threadIdx.x; j < RSZ; j += 256) H[j] = hist[j];
}

// ---------------------------------------------------------------- reduce Hout -> dso; exclusive-scan Hin over chunks -> ind, dsi
__global__ __launch_bounds__(256) void redscan_kernel(const int* __restrict__ Hout,
                                                      int* __restrict__ Hin,
                                                      int* __restrict__ ind,
                                                      float* __restrict__ dso,
                                                      float* __restrict__ dsi) {
    int d = blockIdx.x * 256 + threadIdx.x;
    if (d >= NN) return;
    int so = 0;
#pragma unroll
    for (int c = 0; c < NCHUNK; ++c) so += Hout[c * NN + d];
    dso[d] = so > 0 ? rsqrtf((float)so) : 1.0f;
    int run = 0;
#pragma unroll
    for (int c = 0; c < NCHUNK; ++c) {
        int t = Hin[c * NN + d];
        Hin[c * NN + d] = run;
        run += t;
    }
    ind[d] = run;
    dsi[d] = run > 0 ? rsqrtf((float)run) : 1.0f;
}

// ---------------------------------------------------------------- scan (row_start)
__global__ __launch_bounds__(256) void scan1_kernel(const int* __restrict__ deg,
                                                    int* __restrict__ rs,
                                                    int* __restrict__ bsum, int N) {
    __shared__ int lds[256];
    int t = threadIdx.x, b = blockIdx.x;
    int base = b * 1024 + t * 4;
    int v0 = 0, v1 = 0, v2 = 0, v3 = 0;
    if (base + 0 < N) v0 = deg[base + 0];
    if (base + 1 < N) v1 = deg[base + 1];
    if (base + 2 < N) v2 = deg[base + 2];
    if (base + 3 < N) v3 = deg[base + 3];
    lds[t] = v0 + v1 + v2 + v3;
    __syncthreads();
    for (int off = 1; off < 256; off <<= 1) {
        int add = (t >= off) ? lds[t - off] : 0;
        __syncthreads();
        lds[t] += add;
        __syncthreads();
    }
    int excl = (t > 0) ? lds[t - 1] : 0;
    if (t == 255) bsum[b] = lds[255];
    int r0 = excl + v0, r1 = r0 + v1, r2 = r1 + v2, r3 = r2 + v3;
    if (base + 0 < N) rs[base + 0] = r0;
    if (base + 1 < N) rs[base + 1] = r1;
    if (base + 2 < N) rs[base + 2] = r2;
    if (base + 3 < N) rs[base + 3] = r3;
}

__global__ void scan2_kernel(int* __restrict__ bsum, int NB) {
    __shared__ int lds[128];
    int t = threadIdx.x;
    lds[t] = (t < NB) ? bsum[t] : 0;
    __syncthreads();
    for (int off = 1; off < 128; off <<= 1) {
        int add = (t >= off) ? lds[t - off] : 0;
        __syncthreads();
        lds[t] += add;
        __syncthreads();
    }
    if (t < NB) bsum[t] = (t > 0) ? lds[t - 1] : 0;
}

// scan3: rs = exclusive row start; also fold rs into every Hin[c][i] (global slot bases)
__global__ void scan3_kernel(int* __restrict__ rs, const int* __restrict__ deg,
                             const int* __restrict__ bsum, int* __restrict__ Hin, int N) {
    int i = blockIdx.x * blockDim.x + threadIdx.x;
    if (i < N) {
        int v = rs[i] - deg[i] + bsum[i >> 10];
        rs[i] = v;
#pragma unroll
        for (int c = 0; c < NCHUNK; ++c) Hin[c * NN + i] += v;
    }
}

// ---------------------------------------------------------------- CSR fill (counting sort, no global atomics)
__global__ __launch_bounds__(256) void fill_kernel(const int* __restrict__ src,
                                                   const int* __restrict__ dst,
                                                   const int* __restrict__ Hin,
                                                   int* __restrict__ eidx) {
    __shared__ int cnt[RSZ];
    const int c = blockIdx.x, r = blockIdx.y;
    const int r0 = r * RSZ;
    for (int j = threadIdx.x; j < RSZ; j += 256) cnt[j] = 0;
    __syncthreads();
    const int4* ps = (const int4*)(src + c * CHSZ);
    const int4* pd = (const int4*)(dst + c * CHSZ);
    const int* Hc = Hin + c * NN;
    for (int i = threadIdx.x; i < CHSZ / 4; i += 256) {
        int4 s4 = ps[i];
        int4 d4 = pd[i];
        int ss[4] = {s4.x, s4.y, s4.z, s4.w};
        int dd[4] = {d4.x, d4.y, d4.z, d4.w};
#pragma unroll
        for (int k = 0; k < 4; ++k) {
            unsigned a = (unsigned)(dd[k] - r0);
            if (a < RSZ) {
                int local = atomicAdd(&cnt[a], 1);
                eidx[Hc[dd[k]] + local] = ss[k];
            }
        }
    }
}

// ---------------------------------------------------------------- weight prep: bf16 transpose WT[n][k], pad rows to npad (zeros)
struct PrepBatch {
    const float* src[6];
    unsigned short* dst[6];
    int nout[6];
    int npad[6];
};
__global__ __launch_bounds__(256) void prep_kernel(PrepBatch pb) {
    int m = blockIdx.y;
    int npad = pb.npad[m], nout = pb.nout[m];
    int i = blockIdx.x * 256 + threadIdx.x;
    if (i < 128 * npad) {
        int k = i / npad, n = i - k * npad;
        float v = (n < nout) ? pb.src[m][k * nout + n] : 0.0f;
        pb.dst[m][n * 128 + k] = (unsigned short)f2bf(v);
    }
}

// ---------------------------------------------------------------- MFMA dual GEMM
// U[row][c] = dso[row]*(X@W)[row][c] (bf16, pitch upitch, ALL c < NT*16 stored incl. zero-pad)
// V[row][c] = (X@L)[row][c] (+bias)  (f32, pitch vpitch, stored for c < vcols)
// NOTE: X and V may ALIAS (layer-1 in-place) -> no __restrict__ on them.
template <int NT, bool BN, bool BIAS>
__global__ __launch_bounds__(256) void gemm_mfma_kernel(
    const float* X, const unsigned short* __restrict__ WT,
    const unsigned short* __restrict__ LT, const float* __restrict__ bias,
    const float* __restrict__ scale, const float* __restrict__ shift,
    const float* __restrict__ dso, unsigned short* __restrict__ U, float* V,
    int N, int upitch, int vpitch, int vcols) {
    const int tid = threadIdx.x;
    const int w = tid >> 6, l = tid & 63;
    const int lr = l & 15, kg = l >> 4;
    const long row = (long)blockIdx.x * 64 + w * 16 + lr;
    f32x4 accU[NT];
    f32x4 accV[NT];
#pragma unroll
    for (int t = 0; t < NT; ++t) {
        accU[t] = (f32x4)(0.0f);
        accV[t] = (f32x4)(0.0f);
    }

#pragma unroll
    for (int kc = 0; kc < 4; ++kc) {
        const int kb = kc * 32 + kg * 8;
        short8 av;
        if (row < N) {
            float4 x0 = *(const float4*)&X[row * 128 + kb];
            float4 x1 = *(const float4*)&X[row * 128 + kb + 4];
            float xs[8] = {x0.x, x0.y, x0.z, x0.w, x1.x, x1.y, x1.z, x1.w};
            if (BN) {
                float4 s0 = *(const float4*)&scale[kb];
                float4 s1 = *(const float4*)&scale[kb + 4];
                float4 h0 = *(const float4*)&shift[kb];
                float4 h1 = *(const float4*)&shift[kb + 4];
                float ss[8] = {s0.x, s0.y, s0.z, s0.w, s1.x, s1.y, s1.z, s1.w};
                float hh[8] = {h0.x, h0.y, h0.z, h0.w, h1.x, h1.y, h1.z, h1.w};
#pragma unroll
                for (int j = 0; j < 8; ++j) xs[j] = fmaxf(fmaf(xs[j], ss[j], hh[j]), 0.0f);
            }
#pragma unroll
            for (int j = 0; j < 8; ++j) av[j] = f2bf(xs[j]);
        } else {
#pragma unroll
            for (int j = 0; j < 8; ++j) av[j] = 0;
        }
#pragma unroll
        for (int t = 0; t < NT; ++t) {
            short8 bw = *(const short8*)&WT[(t * 16 + lr) * 128 + kb];
            short8 bl = *(const short8*)&LT[(t * 16 + lr) * 128 + kb];
            accU[t] = __builtin_amdgcn_mfma_f32_16x16x32_bf16(av, bw, accU[t], 0, 0, 0);
            accV[t] = __builtin_amdgcn_mfma_f32_16x16x32_bf16(av, bl, accV[t], 0, 0, 0);
        }
    }

    const long rr0 = (long)blockIdx.x * 64 + w * 16 + kg * 4;
#pragma unroll
    for (int t = 0; t < NT; ++t) {
        const int c = t * 16 + lr;
#pragma unroll
        for (int r = 0; r < 4; ++r) {
            const long rr = rr0 + r;
            if (rr < N) {
                float u = accU[t][r] * dso[rr];
                U[rr * upitch + c] = (unsigned short)f2bf(u);
                if (c < vcols) {
                    float v = accV[t][r];
                    if (BIAS) v += bias[c];
                    V[rr * vpitch + c] = v;
                }
            }
        }
    }
}

// ---------------------------------------------------------------- SpMM (bf16 gather, weights pre-folded)
// Y[n][0..D) = dsi[n] * sum_e Uin[eidx_e][0..D) + addB[n][0..D)   (addB MAY ALIAS Y)
// LPR lanes cover one row (16B = 8 bf16 per lane); EPG = 64/LPR edge groups.
// Edge indices staged in LDS (per-wave region, explicit lgkmcnt fences); cross-group
// reduction via LDS. Group g processes edges j = g, g+EPG, ... (partition of [0,m)).
template <int D, int PITCH, int LPR>
__global__ __launch_bounds__(256) void spmm_bf16_kernel(
    const unsigned short* __restrict__ Uin, const float* addB, float* Y,
    const int* __restrict__ eidx, const int* __restrict__ rs,
    const int* __restrict__ deg, const float* __restrict__ dsi, int N) {
    constexpr int EPG = 64 / LPR;
    __shared__ __align__(16) int sE[4][64];
    __shared__ __align__(16) float sR[4][64][8];
    const int wvloc = threadIdx.x >> 6;
    const int wv = blockIdx.x * 4 + wvloc;
    if (wv >= N) return;
    const int lane = threadIdx.x & 63;
    const int lr = lane & (LPR - 1);   // position within row
    const int g = lane / LPR;          // edge group
    const int start = rs[wv];
    const int dg = deg[wv];
    float acc[8] = {};
    for (int j0 = 0; j0 < dg; j0 += 64) {
        const int m = min(64, dg - j0);
        if (lane < m) sE[wvloc][lane] = eidx[start + j0 + lane];
        asm volatile("s_waitcnt lgkmcnt(0)" ::: "memory");
        for (int j = g; j < m; j += EPG) {
            const int s = sE[wvloc][j];
            const uint4 p = *(const uint4*)&Uin[(long)s * PITCH + lr * 8];
            const unsigned pw[4] = {p.x, p.y, p.z, p.w};
#pragma unroll
            for (int q = 0; q < 4; ++q) {
                union { unsigned u; float f; } lo, hi;
                lo.u = pw[q] << 16;
                hi.u = pw[q] & 0xFFFF0000u;
                acc[q * 2] += lo.f;
                acc[q * 2 + 1] += hi.f;
            }
        }
        asm volatile("s_waitcnt lgkmcnt(0)" ::: "memory");
    }
    // cross-group reduce via LDS
    {
        f32x4 t0 = {acc[0], acc[1], acc[2], acc[3]};
        f32x4 t1 = {acc[4], acc[5], acc[6], acc[7]};
        *(f32x4*)&sR[wvloc][lane][0] = t0;
        *(f32x4*)&sR[wvloc][lane][4] = t1;
    }
    asm volatile("s_waitcnt lgkmcnt(0)" ::: "memory");
    if (lane < LPR && lane * 8 < D) {
        f32x4 r0 = (f32x4)(0.0f), r1 = (f32x4)(0.0f);
#pragma unroll
        for (int g2 = 0; g2 < EPG; ++g2) {
            const float* q = &sR[wvloc][g2 * LPR + lane][0];
            r0 += *(const f32x4*)&q[0];
            r1 += *(const f32x4*)&q[4];
        }
        const float di = dsi[wv];
        const long o = (long)wv * D + lane * 8;
        f32x4 b0 = *(const f32x4*)&addB[o];
        f32x4 b1 = *(const f32x4*)&addB[o + 4];
        f32x4 y0 = b0 + r0 * di;
        f32x4 y1 = b1 + r1 * di;
        *(f32x4*)&Y[o] = y0;
        *(f32x4*)&Y[o + 4] = y1;
    }
}

// ---------------------------------------------------------------- BN stats (sum, sumsq per channel)
__global__ __launch_bounds__(256) void bnstats_kernel(const float* __restrict__ P,
                                                      float* __restrict__ sum,
                                                      float* __restrict__ sq, int N) {
    int c = threadIdx.x & 127;
    int half = threadIdx.x >> 7;
    float s = 0.f, q = 0.f;
    for (long r = blockIdx.x * 2 + half; r < N; r += gridDim.x * 2) {
        float v = P[r * 128 + c];
        s += v;
        q += v * v;
    }
    __shared__ float ls[256], lq[256];
    ls[threadIdx.x] = s;
    lq[threadIdx.x] = q;
    __syncthreads();
    if (threadIdx.x < 128) {
        s = ls[threadIdx.x] + ls[threadIdx.x + 128];
        q = lq[threadIdx.x] + lq[threadIdx.x + 128];
        atomicAdd(&sum[c], s);
        atomicAdd(&sq[c], q);
    }
}

__global__ void bnfinal_kernel(const float* __restrict__ sum, const float* __restrict__ sq,
                               const float* __restrict__ g, const float* __restrict__ be,
                               float* __restrict__ scale, float* __restrict__ shift, float invN) {
    int c = threadIdx.x;  // 128 threads
    float mu = sum[c] * invN;
    float var = sq[c] * invN - mu * mu;
    float sc = g[c] * rsqrtf(var + 1e-5f);
    scale[c] = sc;
    shift[c] = be[c] - mu * sc;
}

// ---------------------------------------------------------------- launch
extern "C" void kernel_launch(void* const* d_in, const int* in_sizes, int n_in,
                              void* d_out, int out_size, void* d_ws, size_t ws_size,
                              hipStream_t stream) {
    const float* feat = (const float*)d_in[0];
    const int* src = (const int*)d_in[1];
    const int* dst = (const int*)d_in[2];
    const float* W0 = (const float*)d_in[3];
    const float* L0 = (const float*)d_in[4];
    const float* W1 = (const float*)d_in[5];
    const float* L1 = (const float*)d_in[6];
    const float* W2 = (const float*)d_in[7];
    const float* L2 = (const float*)d_in[8];
    const float* b2 = (const float*)d_in[9];
    const float* g0 = (const float*)d_in[10];
    const float* be0 = (const float*)d_in[11];
    const float* g1 = (const float*)d_in[12];
    const float* be1 = (const float*)d_in[13];
    float* out = (float*)d_out;

    char* w = (char*)d_ws;
    float* bufP = (float*)(w + 0);                           // 51,200,000 B (X / P / V in-place)
    unsigned short* bufU = (unsigned short*)(w + 51200000);  // 25,600,000 B (bf16 U)
    float* V2 = (float*)(w + 76800000);                      // 16,000,000 B (layer2 V f32, pitch 40)
    int* eidx = (int*)(w + 92800000);                        // 6,400,000 B
    int* ind = (int*)(w + 99200000);                         // 400,000 B
    float* dso = (float*)(w + 99600000);                     // 400,000 B
    float* dsi = (float*)(w + 100000000);                    // 400,000 B
    int* rs = (int*)(w + 100400000);                         // 400,000 B
    int* bsum = (int*)(w + 100800000);                       // 512 B
    float* bnsum = (float*)(w + 100801024);                  // 512 B
    float* bnsq = (float*)(w + 100801536);                   // 512 B
    float* scl = (float*)(w + 100802048);                    // 512 B
    float* sht = (float*)(w + 100802560);                    // 512 B
    unsigned short* W0T = (unsigned short*)(w + 100803072);  // 32768 B each (128x128 bf16)
    unsigned short* L0T = (unsigned short*)(w + 100835840);
    unsigned short* W1T = (unsigned short*)(w + 100868608);
    unsigned short* L1T = (unsigned short*)(w + 100901376);
    unsigned short* W2T = (unsigned short*)(w + 100934144);  // 64x128 bf16 = 16384 B
    unsigned short* L2T = (unsigned short*)(w + 100950528);

    // H matrices alias later-written buffers (dead by the time those are written):
    int* Hout = (int*)bufU;  // 12.8 MB <= 25.6 MB; dead after redscan (before gemm0 writes bufU)
    int* Hin = (int*)V2;     // 12.8 MB <= 16 MB; dead after fill (before gemm2 writes V2)

    const int N = NN;
    const int NB = (N + 1023) / 1024;  // 98
    const int GB = (N + 63) / 64;      // 1563 gemm blocks

    // weight prep (independent of graph build)
    PrepBatch pb;
    pb.src[0] = W0; pb.dst[0] = W0T; pb.nout[0] = 128; pb.npad[0] = 128;
    pb.src[1] = L0; pb.dst[1] = L0T; pb.nout[1] = 128; pb.npad[1] = 128;
    pb.src[2] = W1; pb.dst[2] = W1T; pb.nout[2] = 128; pb.npad[2] = 128;
    pb.src[3] = L1; pb.dst[3] = L1T; pb.nout[3] = 128; pb.npad[3] = 128;
    pb.src[4] = W2; pb.dst[4] = W2T; pb.nout[4] = 40;  pb.npad[4] = 64;
    pb.src[5] = L2; pb.dst[5] = L2T; pb.nout[5] = 40;  pb.npad[5] = 64;
    prep_kernel<<<dim3(64, 6), 256, 0, stream>>>(pb);

    // graph build (no global atomics)
    hist_kernel<<<dim3(NCHUNK, NRANGE, 2), 256, 0, stream>>>(src, dst, Hout, Hin);
    redscan_kernel<<<(N + 255) / 256, 256, 0, stream>>>(Hout, Hin, ind, dso, dsi);
    scan1_kernel<<<NB, 256, 0, stream>>>(ind, rs, bsum, N);
    scan2_kernel<<<1, 128, 0, stream>>>(bsum, NB);
    scan3_kernel<<<(N + 255) / 256, 256, 0, stream>>>(rs, ind, bsum, Hin, N);
    fill_kernel<<<dim3(NCHUNK, NRANGE), 256, 0, stream>>>(src, dst, Hin, eidx);

    // ---- layer 0: U0 = dso*(feat@W0) bf16 -> bufU, V0 = feat@L0 -> bufP; P0 = spmm(U0)+V0 -> bufP
    gemm_mfma_kernel<8, false, false><<<GB, 256, 0, stream>>>(
        feat, W0T, L0T, nullptr, nullptr, nullptr, dso, bufU, bufP, N, 128, 128, 128);
    spmm_bf16_kernel<128, 128, 16><<<(N + 3) / 4, 256, 0, stream>>>(
        bufU, bufP, bufP, eidx, rs, ind, dsi, N);
    hipMemsetAsync(bnsum, 0, 1024, stream);
    bnstats_kernel<<<512, 256, 0, stream>>>(bufP, bnsum, bnsq, N);
    bnfinal_kernel<<<1, 128, 0, stream>>>(bnsum, bnsq, g0, be0, scl, sht, 1.0f / N);

    // ---- layer 1: X = bnrelu(P0) on the fly (X/V in-place alias handled: no restrict)
    gemm_mfma_kernel<8, true, false><<<GB, 256, 0, stream>>>(
        bufP, W1T, L1T, nullptr, scl, sht, dso, bufU, bufP, N, 128, 128, 128);
    spmm_bf16_kernel<128, 128, 16><<<(N + 3) / 4, 256, 0, stream>>>(
        bufU, bufP, bufP, eidx, rs, ind, dsi, N);
    hipMemsetAsync(bnsum, 0, 1024, stream);
    bnstats_kernel<<<512, 256, 0, stream>>>(bufP, bnsum, bnsq, N);
    bnfinal_kernel<<<1, 128, 0, stream>>>(bnsum, bnsq, g1, be1, scl, sht, 1.0f / N);

    // ---- layer 2: U2 pitch 64 (bf16, zero-padded cols 40..63), V2 pitch 40
    gemm_mfma_kernel<4, true, true><<<GB, 256, 0, stream>>>(
        bufP, W2T, L2T, b2, scl, sht, dso, bufU, V2, N, 64, 40, 40);
    spmm_bf16_kernel<40, 64, 8><<<(N + 3) / 4, 256, 0, stream>>>(
        bufU, V2, out, eidx, rs, ind, dsi, N);
}

// Round 7
// 506.016 us; speedup vs baseline: 1.8449x; 1.1871x over previous
//
#include <hip/hip_runtime.h>

#define NN 100000
#define NE 1600000
#define NCHUNK 32
#define CHSZ (NE / NCHUNK)   // 50000 edges per chunk
#define NRANGE 8
#define RSZ (NN / NRANGE)    // 12500 nodes per range

typedef short short8 __attribute__((ext_vector_type(8)));
typedef float f32x4 __attribute__((ext_vector_type(4)));

static __device__ __forceinline__ short f2bf(float f) {
    union { float f; unsigned u; } x;
    x.f = f;
    unsigned r = x.u + 0x7FFFu + ((x.u >> 16) & 1u);
    return (short)(r >> 16);
}

// ---------------------------------------------------------------- per-chunk histograms (no global atomics)
__global__ __launch_bounds__(256) void hist_kernel(const int* __restrict__ src,
                                                   const int* __restrict__ dst,
                                                   int* __restrict__ Hout,
                                                   int* __restrict__ Hin) {
    __shared__ int hist[RSZ];
    const int c = blockIdx.x, r = blockIdx.y, z = blockIdx.z;
    const int r0 = r * RSZ;
    for (int j = threadIdx.x; j < RSZ; j += 256) hist[j] = 0;
    __syncthreads();
    const int4* p = (const int4*)((z ? dst : src) + c * CHSZ);
    for (int i = threadIdx.x; i < CHSZ / 4; i += 256) {
        int4 v = p[i];
        unsigned a;
        a = (unsigned)(v.x - r0); if (a < RSZ) atomicAdd(&hist[a], 1);
        a = (unsigned)(v.y - r0); if (a < RSZ) atomicAdd(&hist[a], 1);
        a = (unsigned)(v.z - r0); if (a < RSZ) atomicAdd(&hist[a], 1);
        a = (unsigned)(v.w - r0); if (a < RSZ) atomicAdd(&hist[a], 1);
    }
    __syncthreads();
    int* H = (z ? Hin : Hout) + c * NN + r0;
    for (int j = threadIdx.x; j < RSZ; j += 256) H[j] = hist[j];
}

// ---------------------------------------------------------------- reduce Hout -> dso; exclusive-scan Hin over chunks -> ind, dsi
__global__ __launch_bounds__(256) void redscan_kernel(const int* __restrict__ Hout,
                                                      int* __restrict__ Hin,
                                                      int* __restrict__ ind,
                                                      float* __restrict__ dso,
                                                      float* __restrict__ dsi) {
    int d = blockIdx.x * 256 + threadIdx.x;
    if (d >= NN) return;
    int so = 0;
#pragma unroll
    for (int c = 0; c < NCHUNK; ++c) so += Hout[c * NN + d];
    dso[d] = so > 0 ? rsqrtf((float)so) : 1.0f;
    int run = 0;
#pragma unroll
    for (int c = 0; c < NCHUNK; ++c) {
        int t = Hin[c * NN + d];
        Hin[c * NN + d] = run;
        run += t;
    }
    ind[d] = run;
    dsi[d] = run > 0 ? rsqrtf((float)run) : 1.0f;
}

// ---------------------------------------------------------------- scan (row_start)
__global__ __launch_bounds__(256) void scan1_kernel(const int* __restrict__ deg,
                                                    int* __restrict__ rs,
                                                    int* __restrict__ bsum, int N) {
    __shared__ int lds[256];
    int t = threadIdx.x, b = blockIdx.x;
    int base = b * 1024 + t * 4;
    int v0 = 0, v1 = 0, v2 = 0, v3 = 0;
    if (base + 0 < N) v0 = deg[base + 0];
    if (base + 1 < N) v1 = deg[base + 1];
    if (base + 2 < N) v2 = deg[base + 2];
    if (base + 3 < N) v3 = deg[base + 3];
    lds[t] = v0 + v1 + v2 + v3;
    __syncthreads();
    for (int off = 1; off < 256; off <<= 1) {
        int add = (t >= off) ? lds[t - off] : 0;
        __syncthreads();
        lds[t] += add;
        __syncthreads();
    }
    int excl = (t > 0) ? lds[t - 1] : 0;
    if (t == 255) bsum[b] = lds[255];
    int r0 = excl + v0, r1 = r0 + v1, r2 = r1 + v2, r3 = r2 + v3;
    if (base + 0 < N) rs[base + 0] = r0;
    if (base + 1 < N) rs[base + 1] = r1;
    if (base + 2 < N) rs[base + 2] = r2;
    if (base + 3 < N) rs[base + 3] = r3;
}

__global__ void scan2_kernel(int* __restrict__ bsum, int NB) {
    __shared__ int lds[128];
    int t = threadIdx.x;
    lds[t] = (t < NB) ? bsum[t] : 0;
    __syncthreads();
    for (int off = 1; off < 128; off <<= 1) {
        int add = (t >= off) ? lds[t - off] : 0;
        __syncthreads();
        lds[t] += add;
        __syncthreads();
    }
    if (t < NB) bsum[t] = (t > 0) ? lds[t - 1] : 0;
}

// scan3: rs = exclusive row start; also fold rs into every Hin[c][i] (global slot bases)
__global__ void scan3_kernel(int* __restrict__ rs, const int* __restrict__ deg,
                             const int* __restrict__ bsum, int* __restrict__ Hin, int N) {
    int i = blockIdx.x * blockDim.x + threadIdx.x;
    if (i < N) {
        int v = rs[i] - deg[i] + bsum[i >> 10];
        rs[i] = v;
#pragma unroll
        for (int c = 0; c < NCHUNK; ++c) Hin[c * NN + i] += v;
    }
}

// ---------------------------------------------------------------- CSR fill (counting sort, no global atomics)
__global__ __launch_bounds__(256) void fill_kernel(const int* __restrict__ src,
                                                   const int* __restrict__ dst,
                                                   const int* __restrict__ Hin,
                                                   int* __restrict__ eidx) {
    __shared__ int cnt[RSZ];
    const int c = blockIdx.x, r = blockIdx.y;
    const int r0 = r * RSZ;
    for (int j = threadIdx.x; j < RSZ; j += 256) cnt[j] = 0;
    __syncthreads();
    const int4* ps = (const int4*)(src + c * CHSZ);
    const int4* pd = (const int4*)(dst + c * CHSZ);
    const int* Hc = Hin + c * NN;
    for (int i = threadIdx.x; i < CHSZ / 4; i += 256) {
        int4 s4 = ps[i];
        int4 d4 = pd[i];
        int ss[4] = {s4.x, s4.y, s4.z, s4.w};
        int dd[4] = {d4.x, d4.y, d4.z, d4.w};
#pragma unroll
        for (int k = 0; k < 4; ++k) {
            unsigned a = (unsigned)(dd[k] - r0);
            if (a < RSZ) {
                int local = atomicAdd(&cnt[a], 1);
                eidx[Hc[dd[k]] + local] = ss[k];
            }
        }
    }
}

// ---------------------------------------------------------------- weight prep: bf16 transpose WT[n][k], pad rows to npad (zeros)
struct PrepBatch {
    const float* src[6];
    unsigned short* dst[6];
    int nout[6];
    int npad[6];
};
__global__ __launch_bounds__(256) void prep_kernel(PrepBatch pb) {
    int m = blockIdx.y;
    int npad = pb.npad[m], nout = pb.nout[m];
    int i = blockIdx.x * 256 + threadIdx.x;
    if (i < 128 * npad) {
        int k = i / npad, n = i - k * npad;
        float v = (n < nout) ? pb.src[m][k * nout + n] : 0.0f;
        pb.dst[m][n * 128 + k] = (unsigned short)f2bf(v);
    }
}

// ---------------------------------------------------------------- MFMA dual GEMM v2 (B-in-registers, X staged bf16 in LDS)
// Block: 256 thr = 4 waves, 64 rows. Wave w covers CPW cols: w<2 -> U (via WT),
// w>=2 -> V (via LT); c0 = (w&1)*CPW.
// U[row][c] = dso[row]*(X@W)[row][c] (bf16, pitch upitch, all CPW*2 cols stored incl. pad)
// V[row][c] = (X@L)[row][c] (+bias)  (f32, pitch vpitch, stored for c < vcols)
// X and V may ALIAS (in-place): block reads only its own 64 rows (into LDS) before writing.
// LDS swizzle: 16-byte granule g (of 16 per row) of row r stored at position g ^ (r&7).
template <int CPW, bool BN, bool BIAS>
__global__ __launch_bounds__(256) void gemm_mfma2_kernel(
    const float* X, const unsigned short* __restrict__ WT,
    const unsigned short* __restrict__ LT, const float* __restrict__ bias,
    const float* __restrict__ scale, const float* __restrict__ shift,
    const float* __restrict__ dso, unsigned short* U, float* V,
    int N, int upitch, int vpitch, int vcols) {
    constexpr int NCT = CPW / 16;
    __shared__ __align__(16) unsigned short Xs[64][128];  // 16 KB, granule-swizzled
    const int tid = threadIdx.x;
    const long rb = (long)blockIdx.x * 64;

    // ---- stage X -> BN+ReLU -> bf16 LDS: 64 rows x 16 granules x 8 bf16 (1024 items)
#pragma unroll
    for (int i = 0; i < 4; ++i) {
        const int idx = i * 256 + tid;
        const int r = idx >> 4, g = idx & 15;
        const long gr = rb + r;
        float xs[8];
        if (gr < N) {
            float4 a0 = *(const float4*)&X[gr * 128 + g * 8];
            float4 a1 = *(const float4*)&X[gr * 128 + g * 8 + 4];
            xs[0] = a0.x; xs[1] = a0.y; xs[2] = a0.z; xs[3] = a0.w;
            xs[4] = a1.x; xs[5] = a1.y; xs[6] = a1.z; xs[7] = a1.w;
            if (BN) {
                float4 s0 = *(const float4*)&scale[g * 8];
                float4 s1 = *(const float4*)&scale[g * 8 + 4];
                float4 h0 = *(const float4*)&shift[g * 8];
                float4 h1 = *(const float4*)&shift[g * 8 + 4];
                float ss[8] = {s0.x, s0.y, s0.z, s0.w, s1.x, s1.y, s1.z, s1.w};
                float hh[8] = {h0.x, h0.y, h0.z, h0.w, h1.x, h1.y, h1.z, h1.w};
#pragma unroll
                for (int j = 0; j < 8; ++j) xs[j] = fmaxf(fmaf(xs[j], ss[j], hh[j]), 0.0f);
            }
        } else {
#pragma unroll
            for (int j = 0; j < 8; ++j) xs[j] = 0.0f;
        }
        short8 pk;
#pragma unroll
        for (int j = 0; j < 8; ++j) pk[j] = f2bf(xs[j]);
        const int gp = g ^ (r & 7);
        *(short8*)&Xs[r][gp * 8] = pk;
    }

    // ---- B fragments into registers (once per wave)
    const int w = tid >> 6, l = tid & 63;
    const int lr = l & 15, kg = l >> 4;
    const unsigned short* BT = (w < 2) ? WT : LT;
    const int c0 = (w & 1) * CPW;
    short8 bfr[NCT][4];
#pragma unroll
    for (int ct = 0; ct < NCT; ++ct)
#pragma unroll
        for (int kc = 0; kc < 4; ++kc)
            bfr[ct][kc] = *(const short8*)&BT[(c0 + ct * 16 + lr) * 128 + kc * 32 + kg * 8];

    __syncthreads();

    // ---- compute: 4 row-tiles of 16
#pragma unroll 1
    for (int rt = 0; rt < 4; ++rt) {
        f32x4 acc[NCT];
#pragma unroll
        for (int ct = 0; ct < NCT; ++ct) acc[ct] = (f32x4)(0.0f);
        const int xrow = rt * 16 + lr;
#pragma unroll
        for (int kc = 0; kc < 4; ++kc) {
            const int p = (kc * 4 + kg) ^ (lr & 7);
            short8 av = *(const short8*)&Xs[xrow][p * 8];
#pragma unroll
            for (int ct = 0; ct < NCT; ++ct)
                acc[ct] = __builtin_amdgcn_mfma_f32_16x16x32_bf16(av, bfr[ct][kc], acc[ct], 0, 0, 0);
        }
        // epilogue: C/D layout col=lane&15, row=(lane>>4)*4+reg
        const long r0 = rb + rt * 16 + kg * 4;
        if (w < 2) {
#pragma unroll
            for (int ct = 0; ct < NCT; ++ct) {
                const int c = c0 + ct * 16 + lr;
#pragma unroll
                for (int r = 0; r < 4; ++r) {
                    const long rr = r0 + r;
                    if (rr < N) U[rr * upitch + c] = (unsigned short)f2bf(acc[ct][r] * dso[rr]);
                }
            }
        } else {
#pragma unroll
            for (int ct = 0; ct < NCT; ++ct) {
                const int c = c0 + ct * 16 + lr;
                if (c < vcols) {
#pragma unroll
                    for (int r = 0; r < 4; ++r) {
                        const long rr = r0 + r;
                        if (rr < N) {
                            float v = acc[ct][r];
                            if (BIAS) v += bias[c];
                            V[rr * vpitch + c] = v;
                        }
                    }
                }
            }
        }
    }
}

// ---------------------------------------------------------------- SpMM (bf16 gather, weights pre-folded)
// Y[n][0..D) = dsi[n] * sum_e Uin[eidx_e][0..D) + addB[n][0..D)   (addB MAY ALIAS Y)
template <int D, int PITCH, int LPR>
__global__ __launch_bounds__(256) void spmm_bf16_kernel(
    const unsigned short* __restrict__ Uin, const float* addB, float* Y,
    const int* __restrict__ eidx, const int* __restrict__ rs,
    const int* __restrict__ deg, const float* __restrict__ dsi, int N) {
    constexpr int EPG = 64 / LPR;
    __shared__ __align__(16) int sE[4][64];
    __shared__ __align__(16) float sR[4][64][8];
    const int wvloc = threadIdx.x >> 6;
    const int wv = blockIdx.x * 4 + wvloc;
    if (wv >= N) return;
    const int lane = threadIdx.x & 63;
    const int lr = lane & (LPR - 1);   // position within row
    const int g = lane / LPR;          // edge group
    const int start = rs[wv];
    const int dg = deg[wv];
    float acc[8] = {};
    for (int j0 = 0; j0 < dg; j0 += 64) {
        const int m = min(64, dg - j0);
        if (lane < m) sE[wvloc][lane] = eidx[start + j0 + lane];
        asm volatile("s_waitcnt lgkmcnt(0)" ::: "memory");
        for (int j = g; j < m; j += EPG) {
            const int s = sE[wvloc][j];
            const uint4 p = *(const uint4*)&Uin[(long)s * PITCH + lr * 8];
            const unsigned pw[4] = {p.x, p.y, p.z, p.w};
#pragma unroll
            for (int q = 0; q < 4; ++q) {
                union { unsigned u; float f; } lo, hi;
                lo.u = pw[q] << 16;
                hi.u = pw[q] & 0xFFFF0000u;
                acc[q * 2] += lo.f;
                acc[q * 2 + 1] += hi.f;
            }
        }
        asm volatile("s_waitcnt lgkmcnt(0)" ::: "memory");
    }
    // cross-group reduce via LDS
    {
        f32x4 t0 = {acc[0], acc[1], acc[2], acc[3]};
        f32x4 t1 = {acc[4], acc[5], acc[6], acc[7]};
        *(f32x4*)&sR[wvloc][lane][0] = t0;
        *(f32x4*)&sR[wvloc][lane][4] = t1;
    }
    asm volatile("s_waitcnt lgkmcnt(0)" ::: "memory");
    if (lane < LPR && lane * 8 < D) {
        f32x4 r0 = (f32x4)(0.0f), r1 = (f32x4)(0.0f);
#pragma unroll
        for (int g2 = 0; g2 < EPG; ++g2) {
            const float* q = &sR[wvloc][g2 * LPR + lane][0];
            r0 += *(const f32x4*)&q[0];
            r1 += *(const f32x4*)&q[4];
        }
        const float di = dsi[wv];
        const long o = (long)wv * D + lane * 8;
        f32x4 b0 = *(const f32x4*)&addB[o];
        f32x4 b1 = *(const f32x4*)&addB[o + 4];
        f32x4 y0 = b0 + r0 * di;
        f32x4 y1 = b1 + r1 * di;
        *(f32x4*)&Y[o] = y0;
        *(f32x4*)&Y[o + 4] = y1;
    }
}

// ---------------------------------------------------------------- BN stats (sum, sumsq per channel)
__global__ __launch_bounds__(256) void bnstats_kernel(const float* __restrict__ P,
                                                      float* __restrict__ sum,
                                                      float* __restrict__ sq, int N) {
    int c = threadIdx.x & 127;
    int half = threadIdx.x >> 7;
    float s = 0.f, q = 0.f;
    for (long r = blockIdx.x * 2 + half; r < N; r += gridDim.x * 2) {
        float v = P[r * 128 + c];
        s += v;
        q += v * v;
    }
    __shared__ float ls[256], lq[256];
    ls[threadIdx.x] = s;
    lq[threadIdx.x] = q;
    __syncthreads();
    if (threadIdx.x < 128) {
        s = ls[threadIdx.x] + ls[threadIdx.x + 128];
        q = lq[threadIdx.x] + lq[threadIdx.x + 128];
        atomicAdd(&sum[c], s);
        atomicAdd(&sq[c], q);
    }
}

__global__ void bnfinal_kernel(const float* __restrict__ sum, const float* __restrict__ sq,
                               const float* __restrict__ g, const float* __restrict__ be,
                               float* __restrict__ scale, float* __restrict__ shift, float invN) {
    int c = threadIdx.x;  // 128 threads
    float mu = sum[c] * invN;
    float var = sq[c] * invN - mu * mu;
    float sc = g[c] * rsqrtf(var + 1e-5f);
    scale[c] = sc;
    shift[c] = be[c] - mu * sc;
}

// ---------------------------------------------------------------- launch
extern "C" void kernel_launch(void* const* d_in, const int* in_sizes, int n_in,
                              void* d_out, int out_size, void* d_ws, size_t ws_size,
                              hipStream_t stream) {
    const float* feat = (const float*)d_in[0];
    const int* src = (const int*)d_in[1];
    const int* dst = (const int*)d_in[2];
    const float* W0 = (const float*)d_in[3];
    const float* L0 = (const float*)d_in[4];
    const float* W1 = (const float*)d_in[5];
    const float* L1 = (const float*)d_in[6];
    const float* W2 = (const float*)d_in[7];
    const float* L2 = (const float*)d_in[8];
    const float* b2 = (const float*)d_in[9];
    const float* g0 = (const float*)d_in[10];
    const float* be0 = (const float*)d_in[11];
    const float* g1 = (const float*)d_in[12];
    const float* be1 = (const float*)d_in[13];
    float* out = (float*)d_out;

    char* w = (char*)d_ws;
    float* bufP = (float*)(w + 0);                           // 51,200,000 B (X / P / V in-place)
    unsigned short* bufU = (unsigned short*)(w + 51200000);  // 25,600,000 B (bf16 U)
    float* V2 = (float*)(w + 76800000);                      // 16,000,000 B (layer2 V f32, pitch 40)
    int* eidx = (int*)(w + 92800000);                        // 6,400,000 B
    int* ind = (int*)(w + 99200000);                         // 400,000 B
    float* dso = (float*)(w + 99600000);                     // 400,000 B
    float* dsi = (float*)(w + 100000000);                    // 400,000 B
    int* rs = (int*)(w + 100400000);                         // 400,000 B
    int* bsum = (int*)(w + 100800000);                       // 512 B
    float* bnsum = (float*)(w + 100801024);                  // 512 B
    float* bnsq = (float*)(w + 100801536);                   // 512 B
    float* scl = (float*)(w + 100802048);                    // 512 B
    float* sht = (float*)(w + 100802560);                    // 512 B
    unsigned short* W0T = (unsigned short*)(w + 100803072);  // 32768 B each (128x128 bf16)
    unsigned short* L0T = (unsigned short*)(w + 100835840);
    unsigned short* W1T = (unsigned short*)(w + 100868608);
    unsigned short* L1T = (unsigned short*)(w + 100901376);
    unsigned short* W2T = (unsigned short*)(w + 100934144);  // 64x128 bf16 = 16384 B
    unsigned short* L2T = (unsigned short*)(w + 100950528);

    // H matrices alias later-written buffers (dead by the time those are written):
    int* Hout = (int*)bufU;  // 12.8 MB <= 25.6 MB; dead after redscan (before gemm0 writes bufU)
    int* Hin = (int*)V2;     // 12.8 MB <= 16 MB; dead after fill (before gemm2 writes V2)

    const int N = NN;
    const int NB = (N + 1023) / 1024;  // 98
    const int GB = (N + 63) / 64;      // 1563 gemm blocks

    // weight prep (independent of graph build)
    PrepBatch pb;
    pb.src[0] = W0; pb.dst[0] = W0T; pb.nout[0] = 128; pb.npad[0] = 128;
    pb.src[1] = L0; pb.dst[1] = L0T; pb.nout[1] = 128; pb.npad[1] = 128;
    pb.src[2] = W1; pb.dst[2] = W1T; pb.nout[2] = 128; pb.npad[2] = 128;
    pb.src[3] = L1; pb.dst[3] = L1T; pb.nout[3] = 128; pb.npad[3] = 128;
    pb.src[4] = W2; pb.dst[4] = W2T; pb.nout[4] = 40;  pb.npad[4] = 64;
    pb.src[5] = L2; pb.dst[5] = L2T; pb.nout[5] = 40;  pb.npad[5] = 64;
    prep_kernel<<<dim3(64, 6), 256, 0, stream>>>(pb);

    // graph build (no global atomics)
    hist_kernel<<<dim3(NCHUNK, NRANGE, 2), 256, 0, stream>>>(src, dst, Hout, Hin);
    redscan_kernel<<<(N + 255) / 256, 256, 0, stream>>>(Hout, Hin, ind, dso, dsi);
    scan1_kernel<<<NB, 256, 0, stream>>>(ind, rs, bsum, N);
    scan2_kernel<<<1, 128, 0, stream>>>(bsum, NB);
    scan3_kernel<<<(N + 255) / 256, 256, 0, stream>>>(rs, ind, bsum, Hin, N);
    fill_kernel<<<dim3(NCHUNK, NRANGE), 256, 0, stream>>>(src, dst, Hin, eidx);

    // ---- layer 0: U0 = dso*(feat@W0) bf16 -> bufU, V0 = feat@L0 -> bufP; P0 = spmm(U0)+V0 -> bufP
    gemm_mfma2_kernel<64, false, false><<<GB, 256, 0, stream>>>(
        feat, W0T, L0T, nullptr, nullptr, nullptr, dso, bufU, bufP, N, 128, 128, 128);
    spmm_bf16_kernel<128, 128, 16><<<(N + 3) / 4, 256, 0, stream>>>(
        bufU, bufP, bufP, eidx, rs, ind, dsi, N);
    hipMemsetAsync(bnsum, 0, 1024, stream);
    bnstats_kernel<<<512, 256, 0, stream>>>(bufP, bnsum, bnsq, N);
    bnfinal_kernel<<<1, 128, 0, stream>>>(bnsum, bnsq, g0, be0, scl, sht, 1.0f / N);

    // ---- layer 1: X = bnrelu(P0) applied during staging (in-place X/V safe per-block)
    gemm_mfma2_kernel<64, true, false><<<GB, 256, 0, stream>>>(
        bufP, W1T, L1T, nullptr, scl, sht, dso, bufU, bufP, N, 128, 128, 128);
    spmm_bf16_kernel<128, 128, 16><<<(N + 3) / 4, 256, 0, stream>>>(
        bufU, bufP, bufP, eidx, rs, ind, dsi, N);
    hipMemsetAsync(bnsum, 0, 1024, stream);
    bnstats_kernel<<<512, 256, 0, stream>>>(bufP, bnsum, bnsq, N);
    bnfinal_kernel<<<1, 128, 0, stream>>>(bnsum, bnsq, g1, be1, scl, sht, 1.0f / N);

    // ---- layer 2: U2 pitch 64 (bf16, zero-padded cols 40..63), V2 pitch 40
    gemm_mfma2_kernel<32, true, true><<<GB, 256, 0, stream>>>(
        bufP, W2T, L2T, b2, scl, sht, dso, bufU, V2, N, 64, 40, 40);
    spmm_bf16_kernel<40, 64, 8><<<(N + 3) / 4, 256, 0, stream>>>(
        bufU, V2, out, eidx, rs, ind, dsi, N);
}

// Round 8
// 499.527 us; speedup vs baseline: 1.8688x; 1.0130x over previous
//
#include <hip/hip_runtime.h>

#define NN 100000
#define NE 1600000
#define NCHUNK 64
#define CHSZ (NE / NCHUNK)   // 25000 edges per chunk
#define NRANGE 8
#define RSZ (NN / NRANGE)    // 12500 nodes per range

typedef short short8 __attribute__((ext_vector_type(8)));
typedef float f32x4 __attribute__((ext_vector_type(4)));

static __device__ __forceinline__ short f2bf(float f) {
    union { float f; unsigned u; } x;
    x.f = f;
    unsigned r = x.u + 0x7FFFu + ((x.u >> 16) & 1u);
    return (short)(r >> 16);
}

// ---------------------------------------------------------------- per-chunk histograms (no global atomics)
// grid (c, r, z): linear id = c + NCHUNK*r + NCHUNK*NRANGE*z -> XCD = c%8, so all
// 16 readers of chunk c (8 ranges x src/dst) share one XCD's L2 for the chunk data.
__global__ __launch_bounds__(256) void hist_kernel(const int* __restrict__ src,
                                                   const int* __restrict__ dst,
                                                   int* __restrict__ Hout,
                                                   int* __restrict__ Hin) {
    __shared__ int hist[RSZ];
    const int c = blockIdx.x, r = blockIdx.y, z = blockIdx.z;
    const int r0 = r * RSZ;
    for (int j = threadIdx.x; j < RSZ; j += 256) hist[j] = 0;
    __syncthreads();
    const int4* p = (const int4*)((z ? dst : src) + c * CHSZ);
    for (int i = threadIdx.x; i < CHSZ / 4; i += 256) {
        int4 v = p[i];
        unsigned a;
        a = (unsigned)(v.x - r0); if (a < RSZ) atomicAdd(&hist[a], 1);
        a = (unsigned)(v.y - r0); if (a < RSZ) atomicAdd(&hist[a], 1);
        a = (unsigned)(v.z - r0); if (a < RSZ) atomicAdd(&hist[a], 1);
        a = (unsigned)(v.w - r0); if (a < RSZ) atomicAdd(&hist[a], 1);
    }
    __syncthreads();
    int* H = (z ? Hin : Hout) + c * NN + r0;
    for (int j = threadIdx.x; j < RSZ; j += 256) H[j] = hist[j];
}

// ---------------------------------------------------------------- reduce Hout -> dso; exclusive-scan Hin over chunks -> ind, dsi
__global__ __launch_bounds__(256) void redscan_kernel(const int* __restrict__ Hout,
                                                      int* __restrict__ Hin,
                                                      int* __restrict__ ind,
                                                      float* __restrict__ dso,
                                                      float* __restrict__ dsi) {
    int d = blockIdx.x * 256 + threadIdx.x;
    if (d >= NN) return;
    int so = 0;
#pragma unroll 8
    for (int c = 0; c < NCHUNK; ++c) so += Hout[c * NN + d];
    dso[d] = so > 0 ? rsqrtf((float)so) : 1.0f;
    int run = 0;
#pragma unroll 8
    for (int c = 0; c < NCHUNK; ++c) {
        int t = Hin[c * NN + d];
        Hin[c * NN + d] = run;
        run += t;
    }
    ind[d] = run;
    dsi[d] = run > 0 ? rsqrtf((float)run) : 1.0f;
}

// ---------------------------------------------------------------- scan (row_start)
__global__ __launch_bounds__(256) void scan1_kernel(const int* __restrict__ deg,
                                                    int* __restrict__ rs,
                                                    int* __restrict__ bsum, int N) {
    __shared__ int lds[256];
    int t = threadIdx.x, b = blockIdx.x;
    int base = b * 1024 + t * 4;
    int v0 = 0, v1 = 0, v2 = 0, v3 = 0;
    if (base + 0 < N) v0 = deg[base + 0];
    if (base + 1 < N) v1 = deg[base + 1];
    if (base + 2 < N) v2 = deg[base + 2];
    if (base + 3 < N) v3 = deg[base + 3];
    lds[t] = v0 + v1 + v2 + v3;
    __syncthreads();
    for (int off = 1; off < 256; off <<= 1) {
        int add = (t >= off) ? lds[t - off] : 0;
        __syncthreads();
        lds[t] += add;
        __syncthreads();
    }
    int excl = (t > 0) ? lds[t - 1] : 0;
    if (t == 255) bsum[b] = lds[255];
    int r0 = excl + v0, r1 = r0 + v1, r2 = r1 + v2, r3 = r2 + v3;
    if (base + 0 < N) rs[base + 0] = r0;
    if (base + 1 < N) rs[base + 1] = r1;
    if (base + 2 < N) rs[base + 2] = r2;
    if (base + 3 < N) rs[base + 3] = r3;
}

__global__ void scan2_kernel(int* __restrict__ bsum, int NB) {
    __shared__ int lds[128];
    int t = threadIdx.x;
    lds[t] = (t < NB) ? bsum[t] : 0;
    __syncthreads();
    for (int off = 1; off < 128; off <<= 1) {
        int add = (t >= off) ? lds[t - off] : 0;
        __syncthreads();
        lds[t] += add;
        __syncthreads();
    }
    if (t < NB) bsum[t] = (t > 0) ? lds[t - 1] : 0;
}

// scan3: rs = exclusive row start; also fold rs into every Hin[c][i] (global slot bases)
__global__ void scan3_kernel(int* __restrict__ rs, const int* __restrict__ deg,
                             const int* __restrict__ bsum, int* __restrict__ Hin, int N) {
    int i = blockIdx.x * blockDim.x + threadIdx.x;
    if (i < N) {
        int v = rs[i] - deg[i] + bsum[i >> 10];
        rs[i] = v;
#pragma unroll 8
        for (int c = 0; c < NCHUNK; ++c) Hin[c * NN + i] += v;
    }
}

// ---------------------------------------------------------------- CSR fill (counting sort, no global atomics)
// 1-D grid, id = c*NRANGE + r -> XCD = r%8 under round-robin dispatch: all chunk-blocks
// of range r co-reside on one XCD, so the range's ~800 KB eidx write window coalesces
// dirty lines in that XCD's L2 (kills write-allocate amplification).
__global__ __launch_bounds__(256) void fill_kernel(const int* __restrict__ src,
                                                   const int* __restrict__ dst,
                                                   const int* __restrict__ Hin,
                                                   int* __restrict__ eidx) {
    __shared__ int cnt[RSZ];
    const int c = blockIdx.x >> 3, r = blockIdx.x & 7;
    const int r0 = r * RSZ;
    for (int j = threadIdx.x; j < RSZ; j += 256) cnt[j] = 0;
    __syncthreads();
    const int4* ps = (const int4*)(src + c * CHSZ);
    const int4* pd = (const int4*)(dst + c * CHSZ);
    const int* Hc = Hin + c * NN;
    for (int i = threadIdx.x; i < CHSZ / 4; i += 256) {
        int4 s4 = ps[i];
        int4 d4 = pd[i];
        int ss[4] = {s4.x, s4.y, s4.z, s4.w};
        int dd[4] = {d4.x, d4.y, d4.z, d4.w};
#pragma unroll
        for (int k = 0; k < 4; ++k) {
            unsigned a = (unsigned)(dd[k] - r0);
            if (a < RSZ) {
                int local = atomicAdd(&cnt[a], 1);
                eidx[Hc[dd[k]] + local] = ss[k];
            }
        }
    }
}

// ---------------------------------------------------------------- weight prep: bf16 transpose WT[n][k], pad rows to npad (zeros)
struct PrepBatch {
    const float* src[6];
    unsigned short* dst[6];
    int nout[6];
    int npad[6];
};
__global__ __launch_bounds__(256) void prep_kernel(PrepBatch pb) {
    int m = blockIdx.y;
    int npad = pb.npad[m], nout = pb.nout[m];
    int i = blockIdx.x * 256 + threadIdx.x;
    if (i < 128 * npad) {
        int k = i / npad, n = i - k * npad;
        float v = (n < nout) ? pb.src[m][k * nout + n] : 0.0f;
        pb.dst[m][n * 128 + k] = (unsigned short)f2bf(v);
    }
}

// ---------------------------------------------------------------- MFMA dual GEMM v2 (B-in-registers, X staged bf16 in LDS)
// Block: 256 thr = 4 waves, 64 rows. Wave w covers CPW cols: w<2 -> U (via WT),
// w>=2 -> V (via LT); c0 = (w&1)*CPW.
// U[row][c] = dso[row]*(X@W)[row][c] (bf16, pitch upitch, all CPW*2 cols stored incl. pad)
// V[row][c] = (X@L)[row][c] (+bias)  (f32, pitch vpitch, stored for c < vcols)
// X and V may ALIAS (in-place): block reads only its own 64 rows (into LDS) before writing.
// LDS swizzle: 16-byte granule g (of 16 per row) of row r stored at position g ^ (r&7).
template <int CPW, bool BN, bool BIAS>
__global__ __launch_bounds__(256) void gemm_mfma2_kernel(
    const float* X, const unsigned short* __restrict__ WT,
    const unsigned short* __restrict__ LT, const float* __restrict__ bias,
    const float* __restrict__ scale, const float* __restrict__ shift,
    const float* __restrict__ dso, unsigned short* U, float* V,
    int N, int upitch, int vpitch, int vcols) {
    constexpr int NCT = CPW / 16;
    __shared__ __align__(16) unsigned short Xs[64][128];  // 16 KB, granule-swizzled
    const int tid = threadIdx.x;
    const long rb = (long)blockIdx.x * 64;

    // ---- stage X -> BN+ReLU -> bf16 LDS: 64 rows x 16 granules x 8 bf16 (1024 items)
#pragma unroll
    for (int i = 0; i < 4; ++i) {
        const int idx = i * 256 + tid;
        const int r = idx >> 4, g = idx & 15;
        const long gr = rb + r;
        float xs[8];
        if (gr < N) {
            float4 a0 = *(const float4*)&X[gr * 128 + g * 8];
            float4 a1 = *(const float4*)&X[gr * 128 + g * 8 + 4];
            xs[0] = a0.x; xs[1] = a0.y; xs[2] = a0.z; xs[3] = a0.w;
            xs[4] = a1.x; xs[5] = a1.y; xs[6] = a1.z; xs[7] = a1.w;
            if (BN) {
                float4 s0 = *(const float4*)&scale[g * 8];
                float4 s1 = *(const float4*)&scale[g * 8 + 4];
                float4 h0 = *(const float4*)&shift[g * 8];
                float4 h1 = *(const float4*)&shift[g * 8 + 4];
                float ss[8] = {s0.x, s0.y, s0.z, s0.w, s1.x, s1.y, s1.z, s1.w};
                float hh[8] = {h0.x, h0.y, h0.z, h0.w, h1.x, h1.y, h1.z, h1.w};
#pragma unroll
                for (int j = 0; j < 8; ++j) xs[j] = fmaxf(fmaf(xs[j], ss[j], hh[j]), 0.0f);
            }
        } else {
#pragma unroll
            for (int j = 0; j < 8; ++j) xs[j] = 0.0f;
        }
        short8 pk;
#pragma unroll
        for (int j = 0; j < 8; ++j) pk[j] = f2bf(xs[j]);
        const int gp = g ^ (r & 7);
        *(short8*)&Xs[r][gp * 8] = pk;
    }

    // ---- B fragments into registers (once per wave)
    const int w = tid >> 6, l = tid & 63;
    const int lr = l & 15, kg = l >> 4;
    const unsigned short* BT = (w < 2) ? WT : LT;
    const int c0 = (w & 1) * CPW;
    short8 bfr[NCT][4];
#pragma unroll
    for (int ct = 0; ct < NCT; ++ct)
#pragma unroll
        for (int kc = 0; kc < 4; ++kc)
            bfr[ct][kc] = *(const short8*)&BT[(c0 + ct * 16 + lr) * 128 + kc * 32 + kg * 8];

    __syncthreads();

    // ---- compute: 4 row-tiles of 16
#pragma unroll 1
    for (int rt = 0; rt < 4; ++rt) {
        f32x4 acc[NCT];
#pragma unroll
        for (int ct = 0; ct < NCT; ++ct) acc[ct] = (f32x4)(0.0f);
        const int xrow = rt * 16 + lr;
#pragma unroll
        for (int kc = 0; kc < 4; ++kc) {
            const int p = (kc * 4 + kg) ^ (lr & 7);
            short8 av = *(const short8*)&Xs[xrow][p * 8];
#pragma unroll
            for (int ct = 0; ct < NCT; ++ct)
                acc[ct] = __builtin_amdgcn_mfma_f32_16x16x32_bf16(av, bfr[ct][kc], acc[ct], 0, 0, 0);
        }
        // epilogue: C/D layout col=lane&15, row=(lane>>4)*4+reg
        const long r0 = rb + rt * 16 + kg * 4;
        if (w < 2) {
#pragma unroll
            for (int ct = 0; ct < NCT; ++ct) {
                const int c = c0 + ct * 16 + lr;
#pragma unroll
                for (int r = 0; r < 4; ++r) {
                    const long rr = r0 + r;
                    if (rr < N) U[rr * upitch + c] = (unsigned short)f2bf(acc[ct][r] * dso[rr]);
                }
            }
        } else {
#pragma unroll
            for (int ct = 0; ct < NCT; ++ct) {
                const int c = c0 + ct * 16 + lr;
                if (c < vcols) {
#pragma unroll
                    for (int r = 0; r < 4; ++r) {
                        const long rr = r0 + r;
                        if (rr < N) {
                            float v = acc[ct][r];
                            if (BIAS) v += bias[c];
                            V[rr * vpitch + c] = v;
                        }
                    }
                }
            }
        }
    }
}

// ---------------------------------------------------------------- SpMM (bf16 gather, weights pre-folded)
// Y[n][0..D) = dsi[n] * sum_e Uin[eidx_e][0..D) + addB[n][0..D)   (addB MAY ALIAS Y)
template <int D, int PITCH, int LPR>
__global__ __launch_bounds__(256) void spmm_bf16_kernel(
    const unsigned short* __restrict__ Uin, const float* addB, float* Y,
    const int* __restrict__ eidx, const int* __restrict__ rs,
    const int* __restrict__ deg, const float* __restrict__ dsi, int N) {
    constexpr int EPG = 64 / LPR;
    __shared__ __align__(16) int sE[4][64];
    __shared__ __align__(16) float sR[4][64][8];
    const int wvloc = threadIdx.x >> 6;
    const int wv = blockIdx.x * 4 + wvloc;
    if (wv >= N) return;
    const int lane = threadIdx.x & 63;
    const int lr = lane & (LPR - 1);   // position within row
    const int g = lane / LPR;          // edge group
    const int start = rs[wv];
    const int dg = deg[wv];
    float acc[8] = {};
    for (int j0 = 0; j0 < dg; j0 += 64) {
        const int m = min(64, dg - j0);
        if (lane < m) sE[wvloc][lane] = eidx[start + j0 + lane];
        asm volatile("s_waitcnt lgkmcnt(0)" ::: "memory");
        for (int j = g; j < m; j += EPG) {
            const int s = sE[wvloc][j];
            const uint4 p = *(const uint4*)&Uin[(long)s * PITCH + lr * 8];
            const unsigned pw[4] = {p.x, p.y, p.z, p.w};
#pragma unroll
            for (int q = 0; q < 4; ++q) {
                union { unsigned u; float f; } lo, hi;
                lo.u = pw[q] << 16;
                hi.u = pw[q] & 0xFFFF0000u;
                acc[q * 2] += lo.f;
                acc[q * 2 + 1] += hi.f;
            }
        }
        asm volatile("s_waitcnt lgkmcnt(0)" ::: "memory");
    }
    // cross-group reduce via LDS
    {
        f32x4 t0 = {acc[0], acc[1], acc[2], acc[3]};
        f32x4 t1 = {acc[4], acc[5], acc[6], acc[7]};
        *(f32x4*)&sR[wvloc][lane][0] = t0;
        *(f32x4*)&sR[wvloc][lane][4] = t1;
    }
    asm volatile("s_waitcnt lgkmcnt(0)" ::: "memory");
    if (lane < LPR && lane * 8 < D) {
        f32x4 r0 = (f32x4)(0.0f), r1 = (f32x4)(0.0f);
#pragma unroll
        for (int g2 = 0; g2 < EPG; ++g2) {
            const float* q = &sR[wvloc][g2 * LPR + lane][0];
            r0 += *(const f32x4*)&q[0];
            r1 += *(const f32x4*)&q[4];
        }
        const float di = dsi[wv];
        const long o = (long)wv * D + lane * 8;
        f32x4 b0 = *(const f32x4*)&addB[o];
        f32x4 b1 = *(const f32x4*)&addB[o + 4];
        f32x4 y0 = b0 + r0 * di;
        f32x4 y1 = b1 + r1 * di;
        *(f32x4*)&Y[o] = y0;
        *(f32x4*)&Y[o + 4] = y1;
    }
}

// ---------------------------------------------------------------- BN stats (sum, sumsq per channel)
__global__ __launch_bounds__(256) void bnstats_kernel(const float* __restrict__ P,
                                                      float* __restrict__ sum,
                                                      float* __restrict__ sq, int N) {
    int c = threadIdx.x & 127;
    int half = threadIdx.x >> 7;
    float s = 0.f, q = 0.f;
    for (long r = blockIdx.x * 2 + half; r < N; r += gridDim.x * 2) {
        float v = P[r * 128 + c];
        s += v;
        q += v * v;
    }
    __shared__ float ls[256], lq[256];
    ls[threadIdx.x] = s;
    lq[threadIdx.x] = q;
    __syncthreads();
    if (threadIdx.x < 128) {
        s = ls[threadIdx.x] + ls[threadIdx.x + 128];
        q = lq[threadIdx.x] + lq[threadIdx.x + 128];
        atomicAdd(&sum[c], s);
        atomicAdd(&sq[c], q);
    }
}

__global__ void bnfinal_kernel(const float* __restrict__ sum, const float* __restrict__ sq,
                               const float* __restrict__ g, const float* __restrict__ be,
                               float* __restrict__ scale, float* __restrict__ shift, float invN) {
    int c = threadIdx.x;  // 128 threads
    float mu = sum[c] * invN;
    float var = sq[c] * invN - mu * mu;
    float sc = g[c] * rsqrtf(var + 1e-5f);
    scale[c] = sc;
    shift[c] = be[c] - mu * sc;
}

// ---------------------------------------------------------------- launch
extern "C" void kernel_launch(void* const* d_in, const int* in_sizes, int n_in,
                              void* d_out, int out_size, void* d_ws, size_t ws_size,
                              hipStream_t stream) {
    const float* feat = (const float*)d_in[0];
    const int* src = (const int*)d_in[1];
    const int* dst = (const int*)d_in[2];
    const float* W0 = (const float*)d_in[3];
    const float* L0 = (const float*)d_in[4];
    const float* W1 = (const float*)d_in[5];
    const float* L1 = (const float*)d_in[6];
    const float* W2 = (const float*)d_in[7];
    const float* L2 = (const float*)d_in[8];
    const float* b2 = (const float*)d_in[9];
    const float* g0 = (const float*)d_in[10];
    const float* be0 = (const float*)d_in[11];
    const float* g1 = (const float*)d_in[12];
    const float* be1 = (const float*)d_in[13];
    float* out = (float*)d_out;

    char* w = (char*)d_ws;
    float* bufP = (float*)(w + 0);                           // 51,200,000 B (X / P / V in-place)
    unsigned short* bufU = (unsigned short*)(w + 51200000);  // 25,600,000 B (bf16 U)
    float* V2 = (float*)(w + 76800000);                      // 16,000,000 B (layer2 V f32, pitch 40)
    int* eidx = (int*)(w + 92800000);                        // 6,400,000 B
    int* ind = (int*)(w + 99200000);                         // 400,000 B
    float* dso = (float*)(w + 99600000);                     // 400,000 B
    float* dsi = (float*)(w + 100000000);                    // 400,000 B
    int* rs = (int*)(w + 100400000);                         // 400,000 B
    int* bsum = (int*)(w + 100800000);                       // 512 B
    float* bnsum = (float*)(w + 100801024);                  // 512 B
    float* bnsq = (float*)(w + 100801536);                   // 512 B
    float* scl = (float*)(w + 100802048);                    // 512 B
    float* sht = (float*)(w + 100802560);                    // 512 B
    unsigned short* W0T = (unsigned short*)(w + 100803072);  // 32768 B each (128x128 bf16)
    unsigned short* L0T = (unsigned short*)(w + 100835840);
    unsigned short* W1T = (unsigned short*)(w + 100868608);
    unsigned short* L1T = (unsigned short*)(w + 100901376);
    unsigned short* W2T = (unsigned short*)(w + 100934144);  // 64x128 bf16 = 16384 B
    unsigned short* L2T = (unsigned short*)(w + 100950528);

    // H matrices (NCHUNK=64: 25.6 MB each) alias later-written buffers:
    int* Hout = (int*)bufU;  // 25.6 MB == bufU; dead after redscan (before gemm0 writes bufU)
    int* Hin = (int*)bufP;   // 25.6 MB <= 51.2 MB; dead after fill (before gemm0 writes bufP)

    const int N = NN;
    const int NB = (N + 1023) / 1024;  // 98
    const int GB = (N + 63) / 64;      // 1563 gemm blocks

    // weight prep (independent of graph build)
    PrepBatch pb;
    pb.src[0] = W0; pb.dst[0] = W0T; pb.nout[0] = 128; pb.npad[0] = 128;
    pb.src[1] = L0; pb.dst[1] = L0T; pb.nout[1] = 128; pb.npad[1] = 128;
    pb.src[2] = W1; pb.dst[2] = W1T; pb.nout[2] = 128; pb.npad[2] = 128;
    pb.src[3] = L1; pb.dst[3] = L1T; pb.nout[3] = 128; pb.npad[3] = 128;
    pb.src[4] = W2; pb.dst[4] = W2T; pb.nout[4] = 40;  pb.npad[4] = 64;
    pb.src[5] = L2; pb.dst[5] = L2T; pb.nout[5] = 40;  pb.npad[5] = 64;
    prep_kernel<<<dim3(64, 6), 256, 0, stream>>>(pb);

    // graph build (no global atomics)
    hist_kernel<<<dim3(NCHUNK, NRANGE, 2), 256, 0, stream>>>(src, dst, Hout, Hin);
    redscan_kernel<<<(N + 255) / 256, 256, 0, stream>>>(Hout, Hin, ind, dso, dsi);
    scan1_kernel<<<NB, 256, 0, stream>>>(ind, rs, bsum, N);
    scan2_kernel<<<1, 128, 0, stream>>>(bsum, NB);
    scan3_kernel<<<(N + 255) / 256, 256, 0, stream>>>(rs, ind, bsum, Hin, N);
    fill_kernel<<<NCHUNK * NRANGE, 256, 0, stream>>>(src, dst, Hin, eidx);

    // ---- layer 0: U0 = dso*(feat@W0) bf16 -> bufU, V0 = feat@L0 -> bufP; P0 = spmm(U0)+V0 -> bufP
    gemm_mfma2_kernel<64, false, false><<<GB, 256, 0, stream>>>(
        feat, W0T, L0T, nullptr, nullptr, nullptr, dso, bufU, bufP, N, 128, 128, 128);
    spmm_bf16_kernel<128, 128, 16><<<(N + 3) / 4, 256, 0, stream>>>(
        bufU, bufP, bufP, eidx, rs, ind, dsi, N);
    hipMemsetAsync(bnsum, 0, 1024, stream);
    bnstats_kernel<<<512, 256, 0, stream>>>(bufP, bnsum, bnsq, N);
    bnfinal_kernel<<<1, 128, 0, stream>>>(bnsum, bnsq, g0, be0, scl, sht, 1.0f / N);

    // ---- layer 1: X = bnrelu(P0) applied during staging (in-place X/V safe per-block)
    gemm_mfma2_kernel<64, true, false><<<GB, 256, 0, stream>>>(
        bufP, W1T, L1T, nullptr, scl, sht, dso, bufU, bufP, N, 128, 128, 128);
    spmm_bf16_kernel<128, 128, 16><<<(N + 3) / 4, 256, 0, stream>>>(
        bufU, bufP, bufP, eidx, rs, ind, dsi, N);
    hipMemsetAsync(bnsum, 0, 1024, stream);
    bnstats_kernel<<<512, 256, 0, stream>>>(bufP, bnsum, bnsq, N);
    bnfinal_kernel<<<1, 128, 0, stream>>>(bnsum, bnsq, g1, be1, scl, sht, 1.0f / N);

    // ---- layer 2: U2 pitch 64 (bf16, zero-padded cols 40..63), V2 pitch 40
    gemm_mfma2_kernel<32, true, true><<<GB, 256, 0, stream>>>(
        bufP, W2T, L2T, b2, scl, sht, dso, bufU, V2, N, 64, 40, 40);
    spmm_bf16_kernel<40, 64, 8><<<(N + 3) / 4, 256, 0, stream>>>(
        bufU, V2, out, eidx, rs, ind, dsi, N);
}

// Round 9
// 469.356 us; speedup vs baseline: 1.9889x; 1.0643x over previous
//
#include <hip/hip_runtime.h>

#define NN 100000
#define NE 1600000
#define NCHUNK 64
#define CHSZ (NE / NCHUNK)   // 25000 edges per chunk
#define NRANGE 8
#define RSZ (NN / NRANGE)    // 12500 nodes per range

typedef short short8 __attribute__((ext_vector_type(8)));
typedef float f32x4 __attribute__((ext_vector_type(4)));

static __device__ __forceinline__ short f2bf(float f) {
    union { float f; unsigned u; } x;
    x.f = f;
    unsigned r = x.u + 0x7FFFu + ((x.u >> 16) & 1u);
    return (short)(r >> 16);
}
static __device__ __forceinline__ float bf2f(unsigned short b) {
    union { unsigned u; float f; } x;
    x.u = ((unsigned)b) << 16;
    return x.f;
}

// ---------------------------------------------------------------- per-chunk histograms (no global atomics, uint16 H)
__global__ __launch_bounds__(256) void hist_kernel(const int* __restrict__ src,
                                                   const int* __restrict__ dst,
                                                   unsigned short* __restrict__ Hout,
                                                   unsigned short* __restrict__ Hin) {
    __shared__ int hist[RSZ];
    const int c = blockIdx.x, r = blockIdx.y, z = blockIdx.z;
    const int r0 = r * RSZ;
    for (int j = threadIdx.x; j < RSZ; j += 256) hist[j] = 0;
    __syncthreads();
    const int4* p = (const int4*)((z ? dst : src) + c * CHSZ);
    for (int i = threadIdx.x; i < CHSZ / 4; i += 256) {
        int4 v = p[i];
        unsigned a;
        a = (unsigned)(v.x - r0); if (a < RSZ) atomicAdd(&hist[a], 1);
        a = (unsigned)(v.y - r0); if (a < RSZ) atomicAdd(&hist[a], 1);
        a = (unsigned)(v.z - r0); if (a < RSZ) atomicAdd(&hist[a], 1);
        a = (unsigned)(v.w - r0); if (a < RSZ) atomicAdd(&hist[a], 1);
    }
    __syncthreads();
    unsigned short* H = (z ? Hin : Hout) + c * NN + r0;
    for (int j = threadIdx.x; j < RSZ; j += 256) H[j] = (unsigned short)hist[j];
}

// ---------------------------------------------------------------- reduce Hout -> dso; exclusive-scan Hin over chunks -> ind, dsi
__global__ __launch_bounds__(256) void redscan_kernel(const unsigned short* __restrict__ Hout,
                                                      unsigned short* __restrict__ Hin,
                                                      int* __restrict__ ind,
                                                      float* __restrict__ dso,
                                                      float* __restrict__ dsi) {
    int d = blockIdx.x * 256 + threadIdx.x;
    if (d >= NN) return;
    int so = 0;
#pragma unroll 8
    for (int c = 0; c < NCHUNK; ++c) so += Hout[c * NN + d];
    dso[d] = so > 0 ? rsqrtf((float)so) : 1.0f;
    int run = 0;
#pragma unroll 8
    for (int c = 0; c < NCHUNK; ++c) {
        int t = Hin[c * NN + d];
        Hin[c * NN + d] = (unsigned short)run;
        run += t;
    }
    ind[d] = run;
    dsi[d] = run > 0 ? rsqrtf((float)run) : 1.0f;
}

// ---------------------------------------------------------------- scan (row_start)
__global__ __launch_bounds__(256) void scan1_kernel(const int* __restrict__ deg,
                                                    int* __restrict__ rs,
                                                    int* __restrict__ bsum, int N) {
    __shared__ int lds[256];
    int t = threadIdx.x, b = blockIdx.x;
    int base = b * 1024 + t * 4;
    int v0 = 0, v1 = 0, v2 = 0, v3 = 0;
    if (base + 0 < N) v0 = deg[base + 0];
    if (base + 1 < N) v1 = deg[base + 1];
    if (base + 2 < N) v2 = deg[base + 2];
    if (base + 3 < N) v3 = deg[base + 3];
    lds[t] = v0 + v1 + v2 + v3;
    __syncthreads();
    for (int off = 1; off < 256; off <<= 1) {
        int add = (t >= off) ? lds[t - off] : 0;
        __syncthreads();
        lds[t] += add;
        __syncthreads();
    }
    int excl = (t > 0) ? lds[t - 1] : 0;
    if (t == 255) bsum[b] = lds[255];
    int r0 = excl + v0, r1 = r0 + v1, r2 = r1 + v2, r3 = r2 + v3;
    if (base + 0 < N) rs[base + 0] = r0;
    if (base + 1 < N) rs[base + 1] = r1;
    if (base + 2 < N) rs[base + 2] = r2;
    if (base + 3 < N) rs[base + 3] = r3;
}

__global__ void scan2_kernel(int* __restrict__ bsum, int NB) {
    __shared__ int lds[128];
    int t = threadIdx.x;
    lds[t] = (t < NB) ? bsum[t] : 0;
    __syncthreads();
    for (int off = 1; off < 128; off <<= 1) {
        int add = (t >= off) ? lds[t - off] : 0;
        __syncthreads();
        lds[t] += add;
        __syncthreads();
    }
    if (t < NB) bsum[t] = (t > 0) ? lds[t - 1] : 0;
}

// scan3: rs = exclusive row start (no H fold; fill adds rs on the fly)
__global__ void scan3_kernel(int* __restrict__ rs, const int* __restrict__ deg,
                             const int* __restrict__ bsum, int N) {
    int i = blockIdx.x * blockDim.x + threadIdx.x;
    if (i < N) rs[i] = rs[i] - deg[i] + bsum[i >> 10];
}

// ---------------------------------------------------------------- CSR fill (counting sort, no global atomics)
// 1-D grid, id = c*NRANGE + r -> XCD = r%8: range's eidx write window coalesces in one L2.
__global__ __launch_bounds__(256) void fill_kernel(const int* __restrict__ src,
                                                   const int* __restrict__ dst,
                                                   const unsigned short* __restrict__ Hin,
                                                   const int* __restrict__ rs,
                                                   int* __restrict__ eidx) {
    __shared__ int cnt[RSZ];
    const int c = blockIdx.x >> 3, r = blockIdx.x & 7;
    const int r0 = r * RSZ;
    for (int j = threadIdx.x; j < RSZ; j += 256) cnt[j] = 0;
    __syncthreads();
    const int4* ps = (const int4*)(src + c * CHSZ);
    const int4* pd = (const int4*)(dst + c * CHSZ);
    const unsigned short* Hc = Hin + c * NN;
    for (int i = threadIdx.x; i < CHSZ / 4; i += 256) {
        int4 s4 = ps[i];
        int4 d4 = pd[i];
        int ss[4] = {s4.x, s4.y, s4.z, s4.w};
        int dd[4] = {d4.x, d4.y, d4.z, d4.w};
#pragma unroll
        for (int k = 0; k < 4; ++k) {
            unsigned a = (unsigned)(dd[k] - r0);
            if (a < RSZ) {
                int local = atomicAdd(&cnt[a], 1);
                eidx[rs[dd[k]] + (int)Hc[dd[k]] + local] = ss[k];
            }
        }
    }
}

// ---------------------------------------------------------------- weight prep: bf16 transpose WT[n][k], pad rows to npad (zeros)
struct PrepBatch {
    const float* src[6];
    unsigned short* dst[6];
    int nout[6];
    int npad[6];
};
__global__ __launch_bounds__(256) void prep_kernel(PrepBatch pb) {
    int m = blockIdx.y;
    int npad = pb.npad[m], nout = pb.nout[m];
    int i = blockIdx.x * 256 + threadIdx.x;
    if (i < 128 * npad) {
        int k = i / npad, n = i - k * npad;
        float v = (n < nout) ? pb.src[m][k * nout + n] : 0.0f;
        pb.dst[m][n * 128 + k] = (unsigned short)f2bf(v);
    }
}

// ---------------------------------------------------------------- MFMA dual GEMM v2 (B-in-registers, X staged bf16 in LDS)
// Wave w: w<2 -> U (via WT), w>=2 -> V (via LT); c0 = (w&1)*CPW.
// U[row][c] = dso[row]*(X@W)[row][c] (bf16, pitch upitch, all cols stored incl. pad)
// V[row][c] = (X@L)[row][c] (+bias)  (bf16 if VBF16 else f32, pitch vpitch, c < vcols)
// X: f32 or bf16 per XBF16. LDS swizzle: granule g of row r at position g ^ (r&7).
template <int CPW, bool BN, bool BIAS, bool XBF16, bool VBF16>
__global__ __launch_bounds__(256) void gemm_mfma2_kernel(
    const void* __restrict__ X, const unsigned short* __restrict__ WT,
    const unsigned short* __restrict__ LT, const float* __restrict__ bias,
    const float* __restrict__ scale, const float* __restrict__ shift,
    const float* __restrict__ dso, unsigned short* __restrict__ U, void* __restrict__ V,
    int N, int upitch, int vpitch, int vcols) {
    constexpr int NCT = CPW / 16;
    __shared__ __align__(16) unsigned short Xs[64][128];  // 16 KB, granule-swizzled
    const int tid = threadIdx.x;
    const long rb = (long)blockIdx.x * 64;

    // ---- stage X -> BN+ReLU -> bf16 LDS: 64 rows x 16 granules x 8 bf16 (1024 items)
#pragma unroll
    for (int i = 0; i < 4; ++i) {
        const int idx = i * 256 + tid;
        const int r = idx >> 4, g = idx & 15;
        const long gr = rb + r;
        float xs[8];
        if (gr < N) {
            if (XBF16) {
                const unsigned short* Xh = (const unsigned short*)X;
                short8 raw = *(const short8*)&Xh[gr * 128 + g * 8];
#pragma unroll
                for (int j = 0; j < 8; ++j) xs[j] = bf2f((unsigned short)raw[j]);
            } else {
                const float* Xf = (const float*)X;
                float4 a0 = *(const float4*)&Xf[gr * 128 + g * 8];
                float4 a1 = *(const float4*)&Xf[gr * 128 + g * 8 + 4];
                xs[0] = a0.x; xs[1] = a0.y; xs[2] = a0.z; xs[3] = a0.w;
                xs[4] = a1.x; xs[5] = a1.y; xs[6] = a1.z; xs[7] = a1.w;
            }
            if (BN) {
                float4 s0 = *(const float4*)&scale[g * 8];
                float4 s1 = *(const float4*)&scale[g * 8 + 4];
                float4 h0 = *(const float4*)&shift[g * 8];
                float4 h1 = *(const float4*)&shift[g * 8 + 4];
                float ss[8] = {s0.x, s0.y, s0.z, s0.w, s1.x, s1.y, s1.z, s1.w};
                float hh[8] = {h0.x, h0.y, h0.z, h0.w, h1.x, h1.y, h1.z, h1.w};
#pragma unroll
                for (int j = 0; j < 8; ++j) xs[j] = fmaxf(fmaf(xs[j], ss[j], hh[j]), 0.0f);
            }
        } else {
#pragma unroll
            for (int j = 0; j < 8; ++j) xs[j] = 0.0f;
        }
        short8 pk;
#pragma unroll
        for (int j = 0; j < 8; ++j) pk[j] = f2bf(xs[j]);
        const int gp = g ^ (r & 7);
        *(short8*)&Xs[r][gp * 8] = pk;
    }

    // ---- B fragments into registers (once per wave)
    const int w = tid >> 6, l = tid & 63;
    const int lr = l & 15, kg = l >> 4;
    const unsigned short* BT = (w < 2) ? WT : LT;
    const int c0 = (w & 1) * CPW;
    short8 bfr[NCT][4];
#pragma unroll
    for (int ct = 0; ct < NCT; ++ct)
#pragma unroll
        for (int kc = 0; kc < 4; ++kc)
            bfr[ct][kc] = *(const short8*)&BT[(c0 + ct * 16 + lr) * 128 + kc * 32 + kg * 8];

    __syncthreads();

    // ---- compute: 4 row-tiles of 16
#pragma unroll 1
    for (int rt = 0; rt < 4; ++rt) {
        f32x4 acc[NCT];
#pragma unroll
        for (int ct = 0; ct < NCT; ++ct) acc[ct] = (f32x4)(0.0f);
        const int xrow = rt * 16 + lr;
#pragma unroll
        for (int kc = 0; kc < 4; ++kc) {
            const int p = (kc * 4 + kg) ^ (lr & 7);
            short8 av = *(const short8*)&Xs[xrow][p * 8];
#pragma unroll
            for (int ct = 0; ct < NCT; ++ct)
                acc[ct] = __builtin_amdgcn_mfma_f32_16x16x32_bf16(av, bfr[ct][kc], acc[ct], 0, 0, 0);
        }
        // epilogue: C/D layout col=lane&15, row=(lane>>4)*4+reg
        const long r0 = rb + rt * 16 + kg * 4;
        if (w < 2) {
#pragma unroll
            for (int ct = 0; ct < NCT; ++ct) {
                const int c = c0 + ct * 16 + lr;
#pragma unroll
                for (int r = 0; r < 4; ++r) {
                    const long rr = r0 + r;
                    if (rr < N) U[rr * upitch + c] = (unsigned short)f2bf(acc[ct][r] * dso[rr]);
                }
            }
        } else {
#pragma unroll
            for (int ct = 0; ct < NCT; ++ct) {
                const int c = c0 + ct * 16 + lr;
                if (c < vcols) {
#pragma unroll
                    for (int r = 0; r < 4; ++r) {
                        const long rr = r0 + r;
                        if (rr < N) {
                            float v = acc[ct][r];
                            if (BIAS) v += bias[c];
                            if (VBF16)
                                ((unsigned short*)V)[rr * vpitch + c] = (unsigned short)f2bf(v);
                            else
                                ((float*)V)[rr * vpitch + c] = v;
                        }
                    }
                }
            }
        }
    }
}

// ---------------------------------------------------------------- SpMM (bf16 gather, weights pre-folded)
// Y[n][0..D) = dsi[n] * sum_e Uin[eidx_e][0..D) + addB[n][0..D)
// BF16IO: addB and Y are bf16 (pitch D); else f32.
template <int D, int PITCH, int LPR, bool BF16IO>
__global__ __launch_bounds__(256) void spmm_bf16_kernel(
    const unsigned short* __restrict__ Uin, const void* __restrict__ addB,
    void* __restrict__ Y, const int* __restrict__ eidx, const int* __restrict__ rs,
    const int* __restrict__ deg, const float* __restrict__ dsi, int N) {
    constexpr int EPG = 64 / LPR;
    __shared__ __align__(16) int sE[4][64];
    __shared__ __align__(16) float sR[4][64][8];
    const int wvloc = threadIdx.x >> 6;
    const int wv = blockIdx.x * 4 + wvloc;
    if (wv >= N) return;
    const int lane = threadIdx.x & 63;
    const int lr = lane & (LPR - 1);   // position within row
    const int g = lane / LPR;          // edge group
    const int start = rs[wv];
    const int dg = deg[wv];
    float acc[8] = {};
    for (int j0 = 0; j0 < dg; j0 += 64) {
        const int m = min(64, dg - j0);
        if (lane < m) sE[wvloc][lane] = eidx[start + j0 + lane];
        asm volatile("s_waitcnt lgkmcnt(0)" ::: "memory");
        for (int j = g; j < m; j += EPG) {
            const int s = sE[wvloc][j];
            const uint4 p = *(const uint4*)&Uin[(long)s * PITCH + lr * 8];
            const unsigned pw[4] = {p.x, p.y, p.z, p.w};
#pragma unroll
            for (int q = 0; q < 4; ++q) {
                union { unsigned u; float f; } lo, hi;
                lo.u = pw[q] << 16;
                hi.u = pw[q] & 0xFFFF0000u;
                acc[q * 2] += lo.f;
                acc[q * 2 + 1] += hi.f;
            }
        }
        asm volatile("s_waitcnt lgkmcnt(0)" ::: "memory");
    }
    // cross-group reduce via LDS
    {
        f32x4 t0 = {acc[0], acc[1], acc[2], acc[3]};
        f32x4 t1 = {acc[4], acc[5], acc[6], acc[7]};
        *(f32x4*)&sR[wvloc][lane][0] = t0;
        *(f32x4*)&sR[wvloc][lane][4] = t1;
    }
    asm volatile("s_waitcnt lgkmcnt(0)" ::: "memory");
    if (lane < LPR && lane * 8 < D) {
        f32x4 r0 = (f32x4)(0.0f), r1 = (f32x4)(0.0f);
#pragma unroll
        for (int g2 = 0; g2 < EPG; ++g2) {
            const float* q = &sR[wvloc][g2 * LPR + lane][0];
            r0 += *(const f32x4*)&q[0];
            r1 += *(const f32x4*)&q[4];
        }
        const float di = dsi[wv];
        const long o = (long)wv * D + lane * 8;
        if (BF16IO) {
            const unsigned short* ab = (const unsigned short*)addB;
            short8 braw = *(const short8*)&ab[o];
            short8 yv;
#pragma unroll
            for (int j = 0; j < 4; ++j)
                yv[j] = f2bf(bf2f((unsigned short)braw[j]) + r0[j] * di);
#pragma unroll
            for (int j = 0; j < 4; ++j)
                yv[4 + j] = f2bf(bf2f((unsigned short)braw[4 + j]) + r1[j] * di);
            *(short8*)&((unsigned short*)Y)[o] = yv;
        } else {
            const float* ab = (const float*)addB;
            f32x4 b0 = *(const f32x4*)&ab[o];
            f32x4 b1 = *(const f32x4*)&ab[o + 4];
            f32x4 y0 = b0 + r0 * di;
            f32x4 y1 = b1 + r1 * di;
            *(f32x4*)&((float*)Y)[o] = y0;
            *(f32x4*)&((float*)Y)[o + 4] = y1;
        }
    }
}

// ---------------------------------------------------------------- BN stats over bf16 P (sum, sumsq per channel)
__global__ __launch_bounds__(256) void bnstats_kernel(const unsigned short* __restrict__ P,
                                                      float* __restrict__ sum,
                                                      float* __restrict__ sq, int N) {
    int c = threadIdx.x & 127;
    int half = threadIdx.x >> 7;
    float s = 0.f, q = 0.f;
    for (long r = blockIdx.x * 2 + half; r < N; r += gridDim.x * 2) {
        float v = bf2f(P[r * 128 + c]);
        s += v;
        q += v * v;
    }
    __shared__ float ls[256], lq[256];
    ls[threadIdx.x] = s;
    lq[threadIdx.x] = q;
    __syncthreads();
    if (threadIdx.x < 128) {
        s = ls[threadIdx.x] + ls[threadIdx.x + 128];
        q = lq[threadIdx.x] + lq[threadIdx.x + 128];
        atomicAdd(&sum[c], s);
        atomicAdd(&sq[c], q);
    }
}

__global__ void bnfinal_kernel(const float* __restrict__ sum, const float* __restrict__ sq,
                               const float* __restrict__ g, const float* __restrict__ be,
                               float* __restrict__ scale, float* __restrict__ shift, float invN) {
    int c = threadIdx.x;  // 128 threads
    float mu = sum[c] * invN;
    float var = sq[c] * invN - mu * mu;
    float sc = g[c] * rsqrtf(var + 1e-5f);
    scale[c] = sc;
    shift[c] = be[c] - mu * sc;
}

// ---------------------------------------------------------------- launch
extern "C" void kernel_launch(void* const* d_in, const int* in_sizes, int n_in,
                              void* d_out, int out_size, void* d_ws, size_t ws_size,
                              hipStream_t stream) {
    const float* feat = (const float*)d_in[0];
    const int* src = (const int*)d_in[1];
    const int* dst = (const int*)d_in[2];
    const float* W0 = (const float*)d_in[3];
    const float* L0 = (const float*)d_in[4];
    const float* W1 = (const float*)d_in[5];
    const float* L1 = (const float*)d_in[6];
    const float* W2 = (const float*)d_in[7];
    const float* L2 = (const float*)d_in[8];
    const float* b2 = (const float*)d_in[9];
    const float* g0 = (const float*)d_in[10];
    const float* be0 = (const float*)d_in[11];
    const float* g1 = (const float*)d_in[12];
    const float* be1 = (const float*)d_in[13];
    float* out = (float*)d_out;

    char* w = (char*)d_ws;
    unsigned short* bufP = (unsigned short*)(w + 0);          // 25,600,000 B (bf16 P0/P1)
    unsigned short* bufU = (unsigned short*)(w + 25600000);   // 25,600,000 B (bf16 U)
    unsigned short* bufV = (unsigned short*)(w + 51200000);   // 25,600,000 B (bf16 V, layers 0/1)
    float* V2 = (float*)(w + 51200000);                       // 16,000,000 B (layer2 V f32; aliases bufV, dead then)
    int* eidx = (int*)(w + 76800000);                         // 6,400,000 B
    int* ind = (int*)(w + 83200000);                          // 400,000 B
    float* dso = (float*)(w + 83600000);                      // 400,000 B
    float* dsi = (float*)(w + 84000000);                      // 400,000 B
    int* rs = (int*)(w + 84400000);                           // 400,000 B
    int* bsum = (int*)(w + 84800000);                         // 512 B
    float* bnsum = (float*)(w + 84801024);                    // 512 B
    float* bnsq = (float*)(w + 84801536);                     // 512 B
    float* scl = (float*)(w + 84802048);                      // 512 B
    float* sht = (float*)(w + 84802560);                      // 512 B
    unsigned short* W0T = (unsigned short*)(w + 84803072);    // 32768 B each (128x128 bf16)
    unsigned short* L0T = (unsigned short*)(w + 84835840);
    unsigned short* W1T = (unsigned short*)(w + 84868608);
    unsigned short* L1T = (unsigned short*)(w + 84901376);
    unsigned short* W2T = (unsigned short*)(w + 84934144);    // 64x128 bf16 = 16384 B
    unsigned short* L2T = (unsigned short*)(w + 84950528);

    // uint16 H matrices (12.8 MB each) alias later-written buffers:
    unsigned short* Hout = bufP;  // dead after redscan; bufP first written by spmm0
    unsigned short* Hin = bufU;   // dead after fill; bufU first written by gemm0 (after fill)

    const int N = NN;
    const int NB = (N + 1023) / 1024;  // 98
    const int GB = (N + 63) / 64;      // 1563 gemm blocks

    // weight prep (independent of graph build)
    PrepBatch pb;
    pb.src[0] = W0; pb.dst[0] = W0T; pb.nout[0] = 128; pb.npad[0] = 128;
    pb.src[1] = L0; pb.dst[1] = L0T; pb.nout[1] = 128; pb.npad[1] = 128;
    pb.src[2] = W1; pb.dst[2] = W1T; pb.nout[2] = 128; pb.npad[2] = 128;
    pb.src[3] = L1; pb.dst[3] = L1T; pb.nout[3] = 128; pb.npad[3] = 128;
    pb.src[4] = W2; pb.dst[4] = W2T; pb.nout[4] = 40;  pb.npad[4] = 64;
    pb.src[5] = L2; pb.dst[5] = L2T; pb.nout[5] = 40;  pb.npad[5] = 64;
    prep_kernel<<<dim3(64, 6), 256, 0, stream>>>(pb);

    // graph build (no global atomics)
    hist_kernel<<<dim3(NCHUNK, NRANGE, 2), 256, 0, stream>>>(src, dst, Hout, Hin);
    redscan_kernel<<<(N + 255) / 256, 256, 0, stream>>>(Hout, Hin, ind, dso, dsi);
    scan1_kernel<<<NB, 256, 0, stream>>>(ind, rs, bsum, N);
    scan2_kernel<<<1, 128, 0, stream>>>(bsum, NB);
    scan3_kernel<<<(N + 255) / 256, 256, 0, stream>>>(rs, ind, bsum, N);
    fill_kernel<<<NCHUNK * NRANGE, 256, 0, stream>>>(src, dst, Hin, rs, eidx);

    // ---- layer 0: U0 = dso*(feat@W0) -> bufU, V0 = feat@L0 -> bufV (bf16); P0 = spmm(U0)+V0 -> bufP (bf16)
    gemm_mfma2_kernel<64, false, false, false, true><<<GB, 256, 0, stream>>>(
        feat, W0T, L0T, nullptr, nullptr, nullptr, dso, bufU, bufV, N, 128, 128, 128);
    spmm_bf16_kernel<128, 128, 16, true><<<(N + 3) / 4, 256, 0, stream>>>(
        bufU, bufV, bufP, eidx, rs, ind, dsi, N);
    hipMemsetAsync(bnsum, 0, 1024, stream);
    bnstats_kernel<<<512, 256, 0, stream>>>(bufP, bnsum, bnsq, N);
    bnfinal_kernel<<<1, 128, 0, stream>>>(bnsum, bnsq, g0, be0, scl, sht, 1.0f / N);

    // ---- layer 1: X = bnrelu(P0) bf16; U -> bufU, V -> bufV; P1 = spmm+V -> bufP
    gemm_mfma2_kernel<64, true, false, true, true><<<GB, 256, 0, stream>>>(
        bufP, W1T, L1T, nullptr, scl, sht, dso, bufU, bufV, N, 128, 128, 128);
    spmm_bf16_kernel<128, 128, 16, true><<<(N + 3) / 4, 256, 0, stream>>>(
        bufU, bufV, bufP, eidx, rs, ind, dsi, N);
    hipMemsetAsync(bnsum, 0, 1024, stream);
    bnstats_kernel<<<512, 256, 0, stream>>>(bufP, bnsum, bnsq, N);
    bnfinal_kernel<<<1, 128, 0, stream>>>(bnsum, bnsq, g1, be1, scl, sht, 1.0f / N);

    // ---- layer 2: U2 pitch 64 bf16 (zero-padded cols 40..63) -> bufU, V2 = X@L2 + b2 (f32, pitch 40)
    gemm_mfma2_kernel<32, true, true, true, false><<<GB, 256, 0, stream>>>(
        bufP, W2T, L2T, b2, scl, sht, dso, bufU, V2, N, 64, 40, 40);
    spmm_bf16_kernel<40, 64, 8, false><<<(N + 3) / 4, 256, 0, stream>>>(
        bufU, V2, out, eidx, rs, ind, dsi, N);
}

// Round 10
// 464.933 us; speedup vs baseline: 2.0079x; 1.0095x over previous
//
#include <hip/hip_runtime.h>

#define NN 100000
#define NE 1600000
#define NCHUNK 64
#define CHSZ (NE / NCHUNK)   // 25000 edges per chunk
#define NRANGE 8
#define RSZ (NN / NRANGE)    // 12500 nodes per range

typedef short short8 __attribute__((ext_vector_type(8)));
typedef float f32x4 __attribute__((ext_vector_type(4)));

static __device__ __forceinline__ short f2bf(float f) {
    union { float f; unsigned u; } x;
    x.f = f;
    unsigned r = x.u + 0x7FFFu + ((x.u >> 16) & 1u);
    return (short)(r >> 16);
}
static __device__ __forceinline__ float bf2f(unsigned short b) {
    union { unsigned u; float f; } x;
    x.u = ((unsigned)b) << 16;
    return x.f;
}

// unpack 8 bf16 (4 words) and accumulate into 8 f32 chains (exact)
static __device__ __forceinline__ void acc8(const uint4 p, float acc[8]) {
    const unsigned pw[4] = {p.x, p.y, p.z, p.w};
#pragma unroll
    for (int q = 0; q < 4; ++q) {
        union { unsigned u; float f; } lo, hi;
        lo.u = pw[q] << 16;
        hi.u = pw[q] & 0xFFFF0000u;
        acc[q * 2] += lo.f;
        acc[q * 2 + 1] += hi.f;
    }
}

// ---------------------------------------------------------------- per-chunk histograms (no global atomics, uint16 H)
__global__ __launch_bounds__(256) void hist_kernel(const int* __restrict__ src,
                                                   const int* __restrict__ dst,
                                                   unsigned short* __restrict__ Hout,
                                                   unsigned short* __restrict__ Hin) {
    __shared__ int hist[RSZ];
    const int c = blockIdx.x, r = blockIdx.y, z = blockIdx.z;
    const int r0 = r * RSZ;
    for (int j = threadIdx.x; j < RSZ; j += 256) hist[j] = 0;
    __syncthreads();
    const int4* p = (const int4*)((z ? dst : src) + c * CHSZ);
    for (int i = threadIdx.x; i < CHSZ / 4; i += 256) {
        int4 v = p[i];
        unsigned a;
        a = (unsigned)(v.x - r0); if (a < RSZ) atomicAdd(&hist[a], 1);
        a = (unsigned)(v.y - r0); if (a < RSZ) atomicAdd(&hist[a], 1);
        a = (unsigned)(v.z - r0); if (a < RSZ) atomicAdd(&hist[a], 1);
        a = (unsigned)(v.w - r0); if (a < RSZ) atomicAdd(&hist[a], 1);
    }
    __syncthreads();
    unsigned short* H = (z ? Hin : Hout) + c * NN + r0;
    for (int j = threadIdx.x; j < RSZ; j += 256) H[j] = (unsigned short)hist[j];
}

// ---------------------------------------------------------------- reduce Hout -> dso; exclusive-scan Hin over chunks -> ind, dsi
__global__ __launch_bounds__(256) void redscan_kernel(const unsigned short* __restrict__ Hout,
                                                      unsigned short* __restrict__ Hin,
                                                      int* __restrict__ ind,
                                                      float* __restrict__ dso,
                                                      float* __restrict__ dsi) {
    int d = blockIdx.x * 256 + threadIdx.x;
    if (d >= NN) return;
    int so = 0;
#pragma unroll 8
    for (int c = 0; c < NCHUNK; ++c) so += Hout[c * NN + d];
    dso[d] = so > 0 ? rsqrtf((float)so) : 1.0f;
    int run = 0;
#pragma unroll 8
    for (int c = 0; c < NCHUNK; ++c) {
        int t = Hin[c * NN + d];
        Hin[c * NN + d] = (unsigned short)run;
        run += t;
    }
    ind[d] = run;
    dsi[d] = run > 0 ? rsqrtf((float)run) : 1.0f;
}

// ---------------------------------------------------------------- scan (row_start)
__global__ __launch_bounds__(256) void scan1_kernel(const int* __restrict__ deg,
                                                    int* __restrict__ rs,
                                                    int* __restrict__ bsum, int N) {
    __shared__ int lds[256];
    int t = threadIdx.x, b = blockIdx.x;
    int base = b * 1024 + t * 4;
    int v0 = 0, v1 = 0, v2 = 0, v3 = 0;
    if (base + 0 < N) v0 = deg[base + 0];
    if (base + 1 < N) v1 = deg[base + 1];
    if (base + 2 < N) v2 = deg[base + 2];
    if (base + 3 < N) v3 = deg[base + 3];
    lds[t] = v0 + v1 + v2 + v3;
    __syncthreads();
    for (int off = 1; off < 256; off <<= 1) {
        int add = (t >= off) ? lds[t - off] : 0;
        __syncthreads();
        lds[t] += add;
        __syncthreads();
    }
    int excl = (t > 0) ? lds[t - 1] : 0;
    if (t == 255) bsum[b] = lds[255];
    int r0 = excl + v0, r1 = r0 + v1, r2 = r1 + v2, r3 = r2 + v3;
    if (base + 0 < N) rs[base + 0] = r0;
    if (base + 1 < N) rs[base + 1] = r1;
    if (base + 2 < N) rs[base + 2] = r2;
    if (base + 3 < N) rs[base + 3] = r3;
}

__global__ void scan2_kernel(int* __restrict__ bsum, int NB) {
    __shared__ int lds[128];
    int t = threadIdx.x;
    lds[t] = (t < NB) ? bsum[t] : 0;
    __syncthreads();
    for (int off = 1; off < 128; off <<= 1) {
        int add = (t >= off) ? lds[t - off] : 0;
        __syncthreads();
        lds[t] += add;
        __syncthreads();
    }
    if (t < NB) bsum[t] = (t > 0) ? lds[t - 1] : 0;
}

// scan3: rs = exclusive row start (no H fold; fill adds rs on the fly)
__global__ void scan3_kernel(int* __restrict__ rs, const int* __restrict__ deg,
                             const int* __restrict__ bsum, int N) {
    int i = blockIdx.x * blockDim.x + threadIdx.x;
    if (i < N) rs[i] = rs[i] - deg[i] + bsum[i >> 10];
}

// ---------------------------------------------------------------- CSR fill (counting sort, no global atomics)
// 1-D grid, id = c*NRANGE + r -> XCD = r%8: range's eidx write window coalesces in one L2.
__global__ __launch_bounds__(256) void fill_kernel(const int* __restrict__ src,
                                                   const int* __restrict__ dst,
                                                   const unsigned short* __restrict__ Hin,
                                                   const int* __restrict__ rs,
                                                   int* __restrict__ eidx) {
    __shared__ int cnt[RSZ];
    const int c = blockIdx.x >> 3, r = blockIdx.x & 7;
    const int r0 = r * RSZ;
    for (int j = threadIdx.x; j < RSZ; j += 256) cnt[j] = 0;
    __syncthreads();
    const int4* ps = (const int4*)(src + c * CHSZ);
    const int4* pd = (const int4*)(dst + c * CHSZ);
    const unsigned short* Hc = Hin + c * NN;
    for (int i = threadIdx.x; i < CHSZ / 4; i += 256) {
        int4 s4 = ps[i];
        int4 d4 = pd[i];
        int ss[4] = {s4.x, s4.y, s4.z, s4.w};
        int dd[4] = {d4.x, d4.y, d4.z, d4.w};
#pragma unroll
        for (int k = 0; k < 4; ++k) {
            unsigned a = (unsigned)(dd[k] - r0);
            if (a < RSZ) {
                int local = atomicAdd(&cnt[a], 1);
                eidx[rs[dd[k]] + (int)Hc[dd[k]] + local] = ss[k];
            }
        }
    }
}

// ---------------------------------------------------------------- weight prep: bf16 transpose WT[n][k], pad rows to npad (zeros)
struct PrepBatch {
    const float* src[6];
    unsigned short* dst[6];
    int nout[6];
    int npad[6];
};
__global__ __launch_bounds__(256) void prep_kernel(PrepBatch pb) {
    int m = blockIdx.y;
    int npad = pb.npad[m], nout = pb.nout[m];
    int i = blockIdx.x * 256 + threadIdx.x;
    if (i < 128 * npad) {
        int k = i / npad, n = i - k * npad;
        float v = (n < nout) ? pb.src[m][k * nout + n] : 0.0f;
        pb.dst[m][n * 128 + k] = (unsigned short)f2bf(v);
    }
}

// ---------------------------------------------------------------- MFMA dual GEMM v2 (B-in-registers, X staged bf16 in LDS)
template <int CPW, bool BN, bool BIAS, bool XBF16, bool VBF16>
__global__ __launch_bounds__(256) void gemm_mfma2_kernel(
    const void* __restrict__ X, const unsigned short* __restrict__ WT,
    const unsigned short* __restrict__ LT, const float* __restrict__ bias,
    const float* __restrict__ scale, const float* __restrict__ shift,
    const float* __restrict__ dso, unsigned short* __restrict__ U, void* __restrict__ V,
    int N, int upitch, int vpitch, int vcols) {
    constexpr int NCT = CPW / 16;
    __shared__ __align__(16) unsigned short Xs[64][128];  // 16 KB, granule-swizzled
    const int tid = threadIdx.x;
    const long rb = (long)blockIdx.x * 64;

    // ---- stage X -> BN+ReLU -> bf16 LDS: 64 rows x 16 granules x 8 bf16 (1024 items)
#pragma unroll
    for (int i = 0; i < 4; ++i) {
        const int idx = i * 256 + tid;
        const int r = idx >> 4, g = idx & 15;
        const long gr = rb + r;
        float xs[8];
        if (gr < N) {
            if (XBF16) {
                const unsigned short* Xh = (const unsigned short*)X;
                short8 raw = *(const short8*)&Xh[gr * 128 + g * 8];
#pragma unroll
                for (int j = 0; j < 8; ++j) xs[j] = bf2f((unsigned short)raw[j]);
            } else {
                const float* Xf = (const float*)X;
                float4 a0 = *(const float4*)&Xf[gr * 128 + g * 8];
                float4 a1 = *(const float4*)&Xf[gr * 128 + g * 8 + 4];
                xs[0] = a0.x; xs[1] = a0.y; xs[2] = a0.z; xs[3] = a0.w;
                xs[4] = a1.x; xs[5] = a1.y; xs[6] = a1.z; xs[7] = a1.w;
            }
            if (BN) {
                float4 s0 = *(const float4*)&scale[g * 8];
                float4 s1 = *(const float4*)&scale[g * 8 + 4];
                float4 h0 = *(const float4*)&shift[g * 8];
                float4 h1 = *(const float4*)&shift[g * 8 + 4];
                float ss[8] = {s0.x, s0.y, s0.z, s0.w, s1.x, s1.y, s1.z, s1.w};
                float hh[8] = {h0.x, h0.y, h0.z, h0.w, h1.x, h1.y, h1.z, h1.w};
#pragma unroll
                for (int j = 0; j < 8; ++j) xs[j] = fmaxf(fmaf(xs[j], ss[j], hh[j]), 0.0f);
            }
        } else {
#pragma unroll
            for (int j = 0; j < 8; ++j) xs[j] = 0.0f;
        }
        short8 pk;
#pragma unroll
        for (int j = 0; j < 8; ++j) pk[j] = f2bf(xs[j]);
        const int gp = g ^ (r & 7);
        *(short8*)&Xs[r][gp * 8] = pk;
    }

    // ---- B fragments into registers (once per wave)
    const int w = tid >> 6, l = tid & 63;
    const int lr = l & 15, kg = l >> 4;
    const unsigned short* BT = (w < 2) ? WT : LT;
    const int c0 = (w & 1) * CPW;
    short8 bfr[NCT][4];
#pragma unroll
    for (int ct = 0; ct < NCT; ++ct)
#pragma unroll
        for (int kc = 0; kc < 4; ++kc)
            bfr[ct][kc] = *(const short8*)&BT[(c0 + ct * 16 + lr) * 128 + kc * 32 + kg * 8];

    __syncthreads();

    // ---- compute: 4 row-tiles of 16
#pragma unroll 1
    for (int rt = 0; rt < 4; ++rt) {
        f32x4 acc[NCT];
#pragma unroll
        for (int ct = 0; ct < NCT; ++ct) acc[ct] = (f32x4)(0.0f);
        const int xrow = rt * 16 + lr;
#pragma unroll
        for (int kc = 0; kc < 4; ++kc) {
            const int p = (kc * 4 + kg) ^ (lr & 7);
            short8 av = *(const short8*)&Xs[xrow][p * 8];
#pragma unroll
            for (int ct = 0; ct < NCT; ++ct)
                acc[ct] = __builtin_amdgcn_mfma_f32_16x16x32_bf16(av, bfr[ct][kc], acc[ct], 0, 0, 0);
        }
        // epilogue: C/D layout col=lane&15, row=(lane>>4)*4+reg
        const long r0 = rb + rt * 16 + kg * 4;
        if (w < 2) {
#pragma unroll
            for (int ct = 0; ct < NCT; ++ct) {
                const int c = c0 + ct * 16 + lr;
#pragma unroll
                for (int r = 0; r < 4; ++r) {
                    const long rr = r0 + r;
                    if (rr < N) U[rr * upitch + c] = (unsigned short)f2bf(acc[ct][r] * dso[rr]);
                }
            }
        } else {
#pragma unroll
            for (int ct = 0; ct < NCT; ++ct) {
                const int c = c0 + ct * 16 + lr;
                if (c < vcols) {
#pragma unroll
                    for (int r = 0; r < 4; ++r) {
                        const long rr = r0 + r;
                        if (rr < N) {
                            float v = acc[ct][r];
                            if (BIAS) v += bias[c];
                            if (VBF16)
                                ((unsigned short*)V)[rr * vpitch + c] = (unsigned short)f2bf(v);
                            else
                                ((float*)V)[rr * vpitch + c] = v;
                        }
                    }
                }
            }
        }
    }
}

// ---------------------------------------------------------------- SpMM (bf16 gather, weights pre-folded)
// Y[n][0..D) = dsi[n] * sum_e Uin[eidx_e][0..D) + addB[n][0..D)
// BF16IO: addB and Y are bf16 (pitch D); else f32. Inner edge loop unrolled 4-deep
// (4 independent gathers in flight per wave); accumulation order identical to serial.
template <int D, int PITCH, int LPR, bool BF16IO>
__global__ __launch_bounds__(256) void spmm_bf16_kernel(
    const unsigned short* __restrict__ Uin, const void* __restrict__ addB,
    void* __restrict__ Y, const int* __restrict__ eidx, const int* __restrict__ rs,
    const int* __restrict__ deg, const float* __restrict__ dsi, int N) {
    constexpr int EPG = 64 / LPR;
    __shared__ __align__(16) int sE[4][64];
    __shared__ __align__(16) float sR[4][64][8];
    const int wvloc = threadIdx.x >> 6;
    const int wv = blockIdx.x * 4 + wvloc;
    if (wv >= N) return;
    const int lane = threadIdx.x & 63;
    const int lr = lane & (LPR - 1);   // position within row
    const int g = lane / LPR;          // edge group
    const int start = rs[wv];
    const int dg = deg[wv];
    float acc[8] = {};
    for (int j0 = 0; j0 < dg; j0 += 64) {
        const int m = min(64, dg - j0);
        if (lane < m) sE[wvloc][lane] = eidx[start + j0 + lane];
        asm volatile("s_waitcnt lgkmcnt(0)" ::: "memory");
        int j = g;
#pragma unroll 1
        for (; j + 3 * EPG < m; j += 4 * EPG) {
            const int s0 = sE[wvloc][j];
            const int s1 = sE[wvloc][j + EPG];
            const int s2 = sE[wvloc][j + 2 * EPG];
            const int s3 = sE[wvloc][j + 3 * EPG];
            const uint4 p0 = *(const uint4*)&Uin[(long)s0 * PITCH + lr * 8];
            const uint4 p1 = *(const uint4*)&Uin[(long)s1 * PITCH + lr * 8];
            const uint4 p2 = *(const uint4*)&Uin[(long)s2 * PITCH + lr * 8];
            const uint4 p3 = *(const uint4*)&Uin[(long)s3 * PITCH + lr * 8];
            acc8(p0, acc);
            acc8(p1, acc);
            acc8(p2, acc);
            acc8(p3, acc);
        }
#pragma unroll 1
        for (; j < m; j += EPG) {
            const int s = sE[wvloc][j];
            const uint4 p = *(const uint4*)&Uin[(long)s * PITCH + lr * 8];
            acc8(p, acc);
        }
        asm volatile("s_waitcnt lgkmcnt(0)" ::: "memory");
    }
    // cross-group reduce via LDS
    {
        f32x4 t0 = {acc[0], acc[1], acc[2], acc[3]};
        f32x4 t1 = {acc[4], acc[5], acc[6], acc[7]};
        *(f32x4*)&sR[wvloc][lane][0] = t0;
        *(f32x4*)&sR[wvloc][lane][4] = t1;
    }
    asm volatile("s_waitcnt lgkmcnt(0)" ::: "memory");
    if (lane < LPR && lane * 8 < D) {
        f32x4 r0 = (f32x4)(0.0f), r1 = (f32x4)(0.0f);
#pragma unroll
        for (int g2 = 0; g2 < EPG; ++g2) {
            const float* q = &sR[wvloc][g2 * LPR + lane][0];
            r0 += *(const f32x4*)&q[0];
            r1 += *(const f32x4*)&q[4];
        }
        const float di = dsi[wv];
        const long o = (long)wv * D + lane * 8;
        if (BF16IO) {
            const unsigned short* ab = (const unsigned short*)addB;
            short8 braw = *(const short8*)&ab[o];
            short8 yv;
#pragma unroll
            for (int j = 0; j < 4; ++j)
                yv[j] = f2bf(bf2f((unsigned short)braw[j]) + r0[j] * di);
#pragma unroll
            for (int j = 0; j < 4; ++j)
                yv[4 + j] = f2bf(bf2f((unsigned short)braw[4 + j]) + r1[j] * di);
            *(short8*)&((unsigned short*)Y)[o] = yv;
        } else {
            const float* ab = (const float*)addB;
            f32x4 b0 = *(const f32x4*)&ab[o];
            f32x4 b1 = *(const f32x4*)&ab[o + 4];
            f32x4 y0 = b0 + r0 * di;
            f32x4 y1 = b1 + r1 * di;
            *(f32x4*)&((float*)Y)[o] = y0;
            *(f32x4*)&((float*)Y)[o + 4] = y1;
        }
    }
}

// ---------------------------------------------------------------- BN stats over bf16 P (sum, sumsq per channel)
__global__ __launch_bounds__(256) void bnstats_kernel(const unsigned short* __restrict__ P,
                                                      float* __restrict__ sum,
                                                      float* __restrict__ sq, int N) {
    int c = threadIdx.x & 127;
    int half = threadIdx.x >> 7;
    float s = 0.f, q = 0.f;
    for (long r = blockIdx.x * 2 + half; r < N; r += gridDim.x * 2) {
        float v = bf2f(P[r * 128 + c]);
        s += v;
        q += v * v;
    }
    __shared__ float ls[256], lq[256];
    ls[threadIdx.x] = s;
    lq[threadIdx.x] = q;
    __syncthreads();
    if (threadIdx.x < 128) {
        s = ls[threadIdx.x] + ls[threadIdx.x + 128];
        q = lq[threadIdx.x] + lq[threadIdx.x + 128];
        atomicAdd(&sum[c], s);
        atomicAdd(&sq[c], q);
    }
}

__global__ void bnfinal_kernel(const float* __restrict__ sum, const float* __restrict__ sq,
                               const float* __restrict__ g, const float* __restrict__ be,
                               float* __restrict__ scale, float* __restrict__ shift, float invN) {
    int c = threadIdx.x;  // 128 threads
    float mu = sum[c] * invN;
    float var = sq[c] * invN - mu * mu;
    float sc = g[c] * rsqrtf(var + 1e-5f);
    scale[c] = sc;
    shift[c] = be[c] - mu * sc;
}

// ---------------------------------------------------------------- launch
extern "C" void kernel_launch(void* const* d_in, const int* in_sizes, int n_in,
                              void* d_out, int out_size, void* d_ws, size_t ws_size,
                              hipStream_t stream) {
    const float* feat = (const float*)d_in[0];
    const int* src = (const int*)d_in[1];
    const int* dst = (const int*)d_in[2];
    const float* W0 = (const float*)d_in[3];
    const float* L0 = (const float*)d_in[4];
    const float* W1 = (const float*)d_in[5];
    const float* L1 = (const float*)d_in[6];
    const float* W2 = (const float*)d_in[7];
    const float* L2 = (const float*)d_in[8];
    const float* b2 = (const float*)d_in[9];
    const float* g0 = (const float*)d_in[10];
    const float* be0 = (const float*)d_in[11];
    const float* g1 = (const float*)d_in[12];
    const float* be1 = (const float*)d_in[13];
    float* out = (float*)d_out;

    char* w = (char*)d_ws;
    unsigned short* bufP = (unsigned short*)(w + 0);          // 25,600,000 B (bf16 P0/P1)
    unsigned short* bufU = (unsigned short*)(w + 25600000);   // 25,600,000 B (bf16 U)
    unsigned short* bufV = (unsigned short*)(w + 51200000);   // 25,600,000 B (bf16 V, layers 0/1)
    float* V2 = (float*)(w + 51200000);                       // 16,000,000 B (layer2 V f32; aliases bufV, dead then)
    int* eidx = (int*)(w + 76800000);                         // 6,400,000 B
    int* ind = (int*)(w + 83200000);                          // 400,000 B
    float* dso = (float*)(w + 83600000);                      // 400,000 B
    float* dsi = (float*)(w + 84000000);                      // 400,000 B
    int* rs = (int*)(w + 84400000);                           // 400,000 B
    int* bsum = (int*)(w + 84800000);                         // 512 B
    float* bnsum = (float*)(w + 84801024);                    // 512 B
    float* bnsq = (float*)(w + 84801536);                     // 512 B
    float* scl = (float*)(w + 84802048);                      // 512 B
    float* sht = (float*)(w + 84802560);                      // 512 B
    unsigned short* W0T = (unsigned short*)(w + 84803072);    // 32768 B each (128x128 bf16)
    unsigned short* L0T = (unsigned short*)(w + 84835840);
    unsigned short* W1T = (unsigned short*)(w + 84868608);
    unsigned short* L1T = (unsigned short*)(w + 84901376);
    unsigned short* W2T = (unsigned short*)(w + 84934144);    // 64x128 bf16 = 16384 B
    unsigned short* L2T = (unsigned short*)(w + 84950528);

    // uint16 H matrices (12.8 MB each) alias later-written buffers:
    unsigned short* Hout = bufP;  // dead after redscan; bufP first written by spmm0
    unsigned short* Hin = bufU;   // dead after fill; bufU first written by gemm0 (after fill)

    const int N = NN;
    const int NB = (N + 1023) / 1024;  // 98
    const int GB = (N + 63) / 64;      // 1563 gemm blocks

    // weight prep (independent of graph build)
    PrepBatch pb;
    pb.src[0] = W0; pb.dst[0] = W0T; pb.nout[0] = 128; pb.npad[0] = 128;
    pb.src[1] = L0; pb.dst[1] = L0T; pb.nout[1] = 128; pb.npad[1] = 128;
    pb.src[2] = W1; pb.dst[2] = W1T; pb.nout[2] = 128; pb.npad[2] = 128;
    pb.src[3] = L1; pb.dst[3] = L1T; pb.nout[3] = 128; pb.npad[3] = 128;
    pb.src[4] = W2; pb.dst[4] = W2T; pb.nout[4] = 40;  pb.npad[4] = 64;
    pb.src[5] = L2; pb.dst[5] = L2T; pb.nout[5] = 40;  pb.npad[5] = 64;
    prep_kernel<<<dim3(64, 6), 256, 0, stream>>>(pb);

    // graph build (no global atomics)
    hist_kernel<<<dim3(NCHUNK, NRANGE, 2), 256, 0, stream>>>(src, dst, Hout, Hin);
    redscan_kernel<<<(N + 255) / 256, 256, 0, stream>>>(Hout, Hin, ind, dso, dsi);
    scan1_kernel<<<NB, 256, 0, stream>>>(ind, rs, bsum, N);
    scan2_kernel<<<1, 128, 0, stream>>>(bsum, NB);
    scan3_kernel<<<(N + 255) / 256, 256, 0, stream>>>(rs, ind, bsum, N);
    fill_kernel<<<NCHUNK * NRANGE, 256, 0, stream>>>(src, dst, Hin, rs, eidx);

    // ---- layer 0: U0 = dso*(feat@W0) -> bufU, V0 = feat@L0 -> bufV (bf16); P0 = spmm(U0)+V0 -> bufP (bf16)
    gemm_mfma2_kernel<64, false, false, false, true><<<GB, 256, 0, stream>>>(
        feat, W0T, L0T, nullptr, nullptr, nullptr, dso, bufU, bufV, N, 128, 128, 128);
    spmm_bf16_kernel<128, 128, 16, true><<<(N + 3) / 4, 256, 0, stream>>>(
        bufU, bufV, bufP, eidx, rs, ind, dsi, N);
    hipMemsetAsync(bnsum, 0, 1024, stream);
    bnstats_kernel<<<512, 256, 0, stream>>>(bufP, bnsum, bnsq, N);
    bnfinal_kernel<<<1, 128, 0, stream>>>(bnsum, bnsq, g0, be0, scl, sht, 1.0f / N);

    // ---- layer 1: X = bnrelu(P0) bf16; U -> bufU, V -> bufV; P1 = spmm+V -> bufP
    gemm_mfma2_kernel<64, true, false, true, true><<<GB, 256, 0, stream>>>(
        bufP, W1T, L1T, nullptr, scl, sht, dso, bufU, bufV, N, 128, 128, 128);
    spmm_bf16_kernel<128, 128, 16, true><<<(N + 3) / 4, 256, 0, stream>>>(
        bufU, bufV, bufP, eidx, rs, ind, dsi, N);
    hipMemsetAsync(bnsum, 0, 1024, stream);
    bnstats_kernel<<<512, 256, 0, stream>>>(bufP, bnsum, bnsq, N);
    bnfinal_kernel<<<1, 128, 0, stream>>>(bnsum, bnsq, g1, be1, scl, sht, 1.0f / N);

    // ---- layer 2: U2 pitch 64 bf16 (zero-padded cols 40..63) -> bufU, V2 = X@L2 + b2 (f32, pitch 40)
    gemm_mfma2_kernel<32, true, true, true, false><<<GB, 256, 0, stream>>>(
        bufP, W2T, L2T, b2, scl, sht, dso, bufU, V2, N, 64, 40, 40);
    spmm_bf16_kernel<40, 64, 8, false><<<(N + 3) / 4, 256, 0, stream>>>(
        bufU, V2, out, eidx, rs, ind, dsi, N);
}